// Round 2
// baseline (673.111 us; speedup 1.0000x reference)
//
#include <hip/hip_runtime.h>
#include <stdint.h>

typedef unsigned short u16;
typedef unsigned int u32;
typedef float f32x4 __attribute__((ext_vector_type(4)));
typedef short short8 __attribute__((ext_vector_type(8)));

#define NBAT 32
#define NSEQ 4096
#define ND 256
#define NSLOT 7

// ---------------- helpers ----------------
__device__ __forceinline__ u32 bf16rne(float f){
  u32 u = __float_as_uint(f);
  u = u + 0x7FFFu + ((u >> 16) & 1u);
  return u >> 16;
}
__device__ __forceinline__ u32 packbf(float a, float b){
  return (bf16rne(a) & 0xFFFFu) | (bf16rne(b) << 16);
}
__device__ __forceinline__ float bflo(u32 u){ return __uint_as_float(u << 16); }
__device__ __forceinline__ float bfhi(u32 u){ return __uint_as_float(u & 0xFFFF0000u); }

__device__ __forceinline__ void gld16(void* lds, const void* g){
  __builtin_amdgcn_global_load_lds(
      (const __attribute__((address_space(1))) u32*)g,
      (__attribute__((address_space(3))) u32*)lds, 16, 0, 0);
}

__device__ __forceinline__ void softmax7(const float* z, float* p){
  float m = fmaxf(fmaxf(fmaxf(z[0], z[1]), fmaxf(z[2], z[3])),
                  fmaxf(fmaxf(z[4], z[5]), z[6]));
  float sum = 0.f;
#pragma unroll
  for (int s = 0; s < 7; ++s){ p[s] = exp2f(z[s] - m); sum += p[s]; }
  float r = 1.f / sum;
#pragma unroll
  for (int s = 0; s < 7; ++s) p[s] = fmaf(p[s], r, 1e-8f);
}

// ---------------- prep: Wkv bf16 concat, bias concat, slots init ----------------
__global__ __launch_bounds__(256) void k_prep(
    const float* __restrict__ wk, const float* __restrict__ wv,
    const float* __restrict__ bk, const float* __restrict__ bv,
    const float* __restrict__ mu, const float* __restrict__ sig,
    const float* __restrict__ noise,
    u16* __restrict__ Wkv, float* __restrict__ biaskv, float* __restrict__ slots){
  const int bid = blockIdx.x, t = threadIdx.x;
  if (bid < 512){
    const float* src = (bid < 256) ? (wk + (size_t)bid*256) : (wv + (size_t)(bid-256)*256);
    Wkv[(size_t)bid*256 + t] = (u16)bf16rne(src[t]);
  } else if (bid == 512){
    biaskv[t] = bk[t];
    biaskv[256 + t] = bv[t];
  } else {
    int r = bid - 513; // 0..223  (b*7+s)
    float sp = logf(1.f + expf(sig[t]));   // softplus
    slots[(size_t)r*256 + t] = mu[t] + sp * noise[(size_t)r*256 + t];
  }
}

// ---------------- K1: LayerNorm(inputs) -> x bf16, one wave per row ----------------
__global__ __launch_bounds__(256) void k_ln_in(
    const float* __restrict__ x, const float* __restrict__ g, const float* __restrict__ b,
    u16* __restrict__ xo){
  const int row = blockIdx.x*4 + (threadIdx.x >> 6);
  const int lane = threadIdx.x & 63;
  const f32x4 v = *(const f32x4*)(x + (size_t)row*ND + lane*4);
  float s  = v[0]+v[1]+v[2]+v[3];
  float s2 = v[0]*v[0]+v[1]*v[1]+v[2]*v[2]+v[3]*v[3];
#pragma unroll
  for (int m = 1; m < 64; m <<= 1){ s += __shfl_xor(s, m); s2 += __shfl_xor(s2, m); }
  const float mean = s * (1.f/256.f);
  const float var  = s2 * (1.f/256.f) - mean*mean;
  const float rstd = rsqrtf(var + 1e-5f);
  const f32x4 gg = *(const f32x4*)(g + lane*4);
  const f32x4 bb = *(const f32x4*)(b + lane*4);
  float y0 = (v[0]-mean)*rstd*gg[0] + bb[0];
  float y1 = (v[1]-mean)*rstd*gg[1] + bb[1];
  float y2 = (v[2]-mean)*rstd*gg[2] + bb[2];
  float y3 = (v[3]-mean)*rstd*gg[3] + bb[3];
  uint2 o; o.x = packbf(y0, y1); o.y = packbf(y2, y3);
  *(uint2*)(xo + (size_t)row*ND + lane*4) = o;
}

// ---------------- K2: kv = x @ Wkv^T + bias  (MFMA bf16, 128x128 tile, BK=64) ----------------
__global__ __launch_bounds__(256) void k_gemm_kv(
    const u16* __restrict__ X, const u16* __restrict__ W,
    const float* __restrict__ biaskv, u16* __restrict__ kv){
  __shared__ __align__(16) u16 At[128*64];
  __shared__ __align__(16) u16 Bt[128*64];
  const int nb = blockIdx.x, mb = blockIdx.y;
  const int tid = threadIdx.x, w = tid >> 6, lane = tid & 63;
  const int wm = w >> 1, wn = w & 1;
  f32x4 acc[4][4];
#pragma unroll
  for (int a = 0; a < 4; ++a)
#pragma unroll
    for (int c = 0; c < 4; ++c) acc[a][c] = (f32x4){0.f,0.f,0.f,0.f};

  const int cl = lane & 7;
  for (int kt = 0; kt < 4; ++kt){
#pragma unroll
    for (int i = 0; i < 4; ++i){
      int R = w*32 + i*8 + (lane >> 3);
      int c = cl ^ (R & 7);                 // source pre-swizzle (st_16B XOR)
      gld16(&At[(w*32 + i*8)*64], X + ((size_t)(mb*128 + R))*256 + kt*64 + c*8);
      gld16(&Bt[(w*32 + i*8)*64], W + ((size_t)(nb*128 + R))*256 + kt*64 + c*8);
    }
    __syncthreads();
#pragma unroll
    for (int kk = 0; kk < 2; ++kk){
      short8 xf[4], wf[4];
#pragma unroll
      for (int xi = 0; xi < 4; ++xi){
        int r = wm*64 + xi*16 + (lane & 15);
        int ch = (kk*4 + (lane >> 4)) ^ (r & 7);
        xf[xi] = *(const short8*)&At[r*64 + ch*8];
      }
#pragma unroll
      for (int wi = 0; wi < 4; ++wi){
        int r = wn*64 + wi*16 + (lane & 15);
        int ch = (kk*4 + (lane >> 4)) ^ (r & 7);
        wf[wi] = *(const short8*)&Bt[r*64 + ch*8];
      }
#pragma unroll
      for (int xi = 0; xi < 4; ++xi)
#pragma unroll
        for (int wi = 0; wi < 4; ++wi)
          acc[xi][wi] = __builtin_amdgcn_mfma_f32_16x16x32_bf16(wf[wi], xf[xi], acc[xi][wi], 0, 0, 0);
    }
    __syncthreads();
  }
  f32x4 bias[4];
#pragma unroll
  for (int wi = 0; wi < 4; ++wi)
    bias[wi] = *(const f32x4*)(biaskv + nb*128 + wn*64 + wi*16 + (lane >> 4)*4);
#pragma unroll
  for (int xi = 0; xi < 4; ++xi){
    size_t m = (size_t)mb*128 + wm*64 + xi*16 + (lane & 15);
    u16* dst = kv + m*512 + nb*128 + wn*64 + (lane >> 4)*4;
#pragma unroll
    for (int wi = 0; wi < 4; ++wi){
      f32x4 c = acc[xi][wi];
      uint2 o;
      o.x = packbf(c[0] + bias[wi][0], c[1] + bias[wi][1]);
      o.y = packbf(c[2] + bias[wi][2], c[3] + bias[wi][3]);
      *(uint2*)(dst + wi*16) = o;
    }
  }
}

// ---------------- K3: q = LN(slots) @ wq^T + bq, pre-scaled by log2(e)/16 ----------------
// wave-cooperative GEMV: wave w computes outputs j = w*16..w*16+15 via coalesced row reads
__global__ __launch_bounds__(256) void k_qproj(
    const float* __restrict__ slots, const float* __restrict__ g, const float* __restrict__ b,
    const float* __restrict__ wq, const float* __restrict__ bq, float* __restrict__ qeff){
  __shared__ __align__(16) float lnv[256];
  __shared__ float red[8];
  const int bs = blockIdx.x, t = threadIdx.x;
  const int w = t >> 6, lane = t & 63;
  float x = slots[(size_t)bs*256 + t];
  float s = x, s2 = x*x;
#pragma unroll
  for (int m = 1; m < 64; m <<= 1){ s += __shfl_xor(s, m); s2 += __shfl_xor(s2, m); }
  if ((t & 63) == 0){ red[t >> 6] = s; red[4 + (t >> 6)] = s2; }
  __syncthreads();
  float ssum = red[0]+red[1]+red[2]+red[3];
  float qsum = red[4]+red[5]+red[6]+red[7];
  float mean = ssum*(1.f/256.f);
  float var  = qsum*(1.f/256.f) - mean*mean;
  float rstd = rsqrtf(var + 1e-5f);
  lnv[t] = (x - mean)*rstd*g[t] + b[t];
  __syncthreads();
  const f32x4 l4 = *(const f32x4*)&lnv[lane*4];
  for (int j = w*64; j < w*64 + 64; ++j){
    const f32x4 r4 = *(const f32x4*)(wq + (size_t)j*256 + lane*4);
    f32x4 p = r4 * l4;
    float d = p[0]+p[1]+p[2]+p[3];
#pragma unroll
    for (int m = 1; m < 64; m <<= 1) d += __shfl_xor(d, m);
    if (lane == 0)
      qeff[(size_t)bs*256 + j] = (d + bq[j]) * 0.09016844f; // log2(e)/16
  }
}

// ---------------- K4: fused logits -> softmax(S) -> partial (p'@v, sum p') ----------------
__global__ __launch_bounds__(256) void k_attn(
    const u16* __restrict__ kv, const float* __restrict__ qeff,
    float* __restrict__ attn_out, float* __restrict__ pacc, float* __restrict__ pw){
  __shared__ __align__(16) float accbuf[4][7][256];
  __shared__ float wsbuf[4][7];
  const int chunk = blockIdx.x, b = blockIdx.y;
  const int tid = threadIdx.x, w = tid >> 6, lane = tid & 63, hi = lane >> 5, lo = lane & 31;
  float qr[7][8];
  {
    const float* qb = qeff + (size_t)b*(NSLOT*256) + lo*8;
#pragma unroll
    for (int s = 0; s < 7; ++s){
      f32x4 q0 = *(const f32x4*)(qb + s*256);
      f32x4 q1 = *(const f32x4*)(qb + s*256 + 4);
      qr[s][0]=q0[0]; qr[s][1]=q0[1]; qr[s][2]=q0[2]; qr[s][3]=q0[3];
      qr[s][4]=q1[0]; qr[s][5]=q1[1]; qr[s][6]=q1[2]; qr[s][7]=q1[3];
    }
  }
  float acc[7][4]; float wsm[7];
#pragma unroll
  for (int s = 0; s < 7; ++s){ acc[s][0]=acc[s][1]=acc[s][2]=acc[s][3]=0.f; wsm[s]=0.f; }

  const size_t bbase = (size_t)b*NSEQ;
  for (int it = 0; it < 16; ++it){
    const int nr = chunk*128 + it*8 + w*2;
    const size_t rowm = (bbase + nr + hi)*512;
    const size_t rowo = (bbase + nr + (1 - hi))*512;
    uint4 k4 = *(const uint4*)(kv + rowm + lo*8);
    float kf[8];
    kf[0]=bflo(k4.x); kf[1]=bfhi(k4.x); kf[2]=bflo(k4.y); kf[3]=bfhi(k4.y);
    kf[4]=bflo(k4.z); kf[5]=bfhi(k4.z); kf[6]=bflo(k4.w); kf[7]=bfhi(k4.w);
    float z[7];
#pragma unroll
    for (int s = 0; s < 7; ++s){
      float d0 = fmaf(qr[s][0],kf[0], fmaf(qr[s][1],kf[1], fmaf(qr[s][2],kf[2], qr[s][3]*kf[3])));
      float d1 = fmaf(qr[s][4],kf[4], fmaf(qr[s][5],kf[5], fmaf(qr[s][6],kf[6], qr[s][7]*kf[7])));
      z[s] = d0 + d1;
    }
#pragma unroll
    for (int m = 1; m < 32; m <<= 1){
#pragma unroll
      for (int s = 0; s < 7; ++s) z[s] += __shfl_xor(z[s], m);
    }
    float zo[7];
#pragma unroll
    for (int s = 0; s < 7; ++s) zo[s] = __shfl_xor(z[s], 32);
    float pm[7], po[7];
    softmax7(z, pm);
    softmax7(zo, po);
    float sel = pm[0];
    sel = (lo==1)?pm[1]:sel; sel = (lo==2)?pm[2]:sel; sel = (lo==3)?pm[3]:sel;
    sel = (lo==4)?pm[4]:sel; sel = (lo==5)?pm[5]:sel; sel = (lo==6)?pm[6]:sel;
    if (lo < 7) attn_out[(bbase + nr + hi)*7 + lo] = sel;
    uint2 va = *(const uint2*)(kv + rowm + 256 + (size_t)lane*4);
    uint2 vb = *(const uint2*)(kv + rowo + 256 + (size_t)lane*4);
    float vm0=bflo(va.x), vm1=bfhi(va.x), vm2=bflo(va.y), vm3=bfhi(va.y);
    float vo0=bflo(vb.x), vo1=bfhi(vb.x), vo2=bflo(vb.y), vo3=bfhi(vb.y);
#pragma unroll
    for (int s = 0; s < 7; ++s){
      acc[s][0] = fmaf(pm[s], vm0, fmaf(po[s], vo0, acc[s][0]));
      acc[s][1] = fmaf(pm[s], vm1, fmaf(po[s], vo1, acc[s][1]));
      acc[s][2] = fmaf(pm[s], vm2, fmaf(po[s], vo2, acc[s][2]));
      acc[s][3] = fmaf(pm[s], vm3, fmaf(po[s], vo3, acc[s][3]));
      wsm[s] += pm[s] + po[s];
    }
  }
#pragma unroll
  for (int s = 0; s < 7; ++s)
    *(f32x4*)&accbuf[w][s][lane*4] = (f32x4){acc[s][0], acc[s][1], acc[s][2], acc[s][3]};
  if (lane == 0){
#pragma unroll
    for (int s = 0; s < 7; ++s) wsbuf[w][s] = wsm[s];
  }
  __syncthreads();
#pragma unroll
  for (int s = 0; s < 7; ++s){
    float sum = accbuf[0][s][tid] + accbuf[1][s][tid] + accbuf[2][s][tid] + accbuf[3][s][tid];
    pacc[((size_t)chunk*NBAT + b)*(NSLOT*256) + s*256 + tid] = sum;
  }
  if (tid < 7)
    pw[((size_t)chunk*NBAT + b)*NSLOT + tid] =
        wsbuf[0][tid] + wsbuf[1][tid] + wsbuf[2][tid] + wsbuf[3][tid];
}

// ---------------- K5: reduce partials -> updates; GRU; LN; MLP; slots update ----------------
// All GEMVs are wave-cooperative: a wave computes one output j at a time with a
// fully-coalesced row read (64 lanes x f32x4 = one 1KB row), vector held in regs.
__global__ __launch_bounds__(768) void k_slot(
    const float* __restrict__ pacc, const float* __restrict__ pw,
    float* __restrict__ slots,
    const float* __restrict__ w_ih, const float* __restrict__ b_ih,
    const float* __restrict__ w_hh, const float* __restrict__ b_hh,
    const float* __restrict__ gm, const float* __restrict__ bm,
    const float* __restrict__ w1, const float* __restrict__ b1,
    const float* __restrict__ w2, const float* __restrict__ b2,
    float* __restrict__ wsum_tot, float* __restrict__ out_slots, int last){
  __shared__ __align__(16) float updk[256], spv[256], lnv[256], hbuf[512];
  __shared__ float gib[768], ghb[768], snew[256];
  __shared__ float pwb[32];
  __shared__ float reds[12], redq[12];
  const int bs = blockIdx.x, t = threadIdx.x;
  const int w = t >> 6, lane = t & 63;
  if (t < 32) pwb[t] = pw[(size_t)t*224 + bs];
  float u = 0.f;
  if (t < 256){
#pragma unroll 8
    for (int c = 0; c < 32; ++c) u += pacc[(size_t)c*57344 + (size_t)bs*256 + t];
    spv[t] = slots[(size_t)bs*256 + t];
  }
  __syncthreads();
  float wst = 0.f;
#pragma unroll
  for (int c = 0; c < 32; ++c) wst += pwb[c];
  const float inv = 1.f / wst;
  if (t == 0) wsum_tot[bs] = wst;
  if (t < 256) updk[t] = u * inv;
  __syncthreads();
  // ---- GRU GEMVs: 12 waves x 64 outputs, coalesced row reads ----
  {
    const f32x4 u4 = *(const f32x4*)&updk[lane*4];
    const f32x4 s4 = *(const f32x4*)&spv[lane*4];
#pragma unroll 4
    for (int jj = 0; jj < 64; ++jj){
      const int j = w*64 + jj;
      const f32x4 wi4 = *(const f32x4*)(w_ih + (size_t)j*256 + lane*4);
      const f32x4 wh4 = *(const f32x4*)(w_hh + (size_t)j*256 + lane*4);
      f32x4 pa = wi4 * u4;
      f32x4 pb = wh4 * s4;
      float da = pa[0]+pa[1]+pa[2]+pa[3];
      float db = pb[0]+pb[1]+pb[2]+pb[3];
#pragma unroll
      for (int m = 1; m < 64; m <<= 1){ da += __shfl_xor(da, m); db += __shfl_xor(db, m); }
      if (lane == 0){ gib[j] = da + b_ih[j]; ghb[j] = db + b_hh[j]; }
    }
  }
  __syncthreads();
  float sp = 0.f;
  if (t < 256){
    float rr = 1.f/(1.f + __expf(-(gib[t] + ghb[t])));
    float zz = 1.f/(1.f + __expf(-(gib[256+t] + ghb[256+t])));
    float xx = gib[512+t] + rr*ghb[512+t];
    xx = fminf(fmaxf(xx, -15.f), 15.f);
    float e2 = __expf(2.f*xx);
    float nn = (e2 - 1.f)/(e2 + 1.f);
    sp = (1.f - zz)*nn + zz*spv[t];
    snew[t] = sp;
  }
  __syncthreads();
  float rs = sp, rq = sp*sp;
#pragma unroll
  for (int m = 1; m < 64; m <<= 1){ rs += __shfl_xor(rs, m); rq += __shfl_xor(rq, m); }
  if ((t & 63) == 0){ reds[t >> 6] = rs; redq[t >> 6] = rq; }
  __syncthreads();
  float ssum = 0.f, qsum = 0.f;
#pragma unroll
  for (int i = 0; i < 12; ++i){ ssum += reds[i]; qsum += redq[i]; }
  const float mean = ssum*(1.f/256.f);
  const float var  = qsum*(1.f/256.f) - mean*mean;
  const float rstd = rsqrtf(var + 1e-5f);
  if (t < 256) lnv[t] = (sp - mean)*rstd*gm[t] + bm[t];
  __syncthreads();
  // ---- MLP layer 1: 512 outputs over 12 waves ----
  {
    const f32x4 l4 = *(const f32x4*)&lnv[lane*4];
    for (int j = w; j < 512; j += 12){
      const f32x4 r4 = *(const f32x4*)(w1 + (size_t)j*256 + lane*4);
      f32x4 p = r4 * l4;
      float d = p[0]+p[1]+p[2]+p[3];
#pragma unroll
      for (int m = 1; m < 64; m <<= 1) d += __shfl_xor(d, m);
      if (lane == 0) hbuf[j] = fmaxf(d + b1[j], 0.f);
    }
  }
  __syncthreads();
  // ---- MLP layer 2: 256 outputs over 12 waves, K=512 (lane owns 8) ----
  {
    const f32x4 h4a = *(const f32x4*)&hbuf[lane*8];
    const f32x4 h4b = *(const f32x4*)&hbuf[lane*8 + 4];
    for (int j = w; j < 256; j += 12){
      const f32x4 r4a = *(const f32x4*)(w2 + (size_t)j*512 + lane*8);
      const f32x4 r4b = *(const f32x4*)(w2 + (size_t)j*512 + lane*8 + 4);
      f32x4 p = r4a * h4a + r4b * h4b;
      float d = p[0]+p[1]+p[2]+p[3];
#pragma unroll
      for (int m = 1; m < 64; m <<= 1) d += __shfl_xor(d, m);
      if (lane == 0){
        float o = snew[j] + d + b2[j];
        slots[(size_t)bs*256 + j] = o;
        if (last) out_slots[(size_t)bs*256 + j] = o;
      }
    }
  }
}

// ---------------- K6: attn /= sum over n ----------------
__global__ __launch_bounds__(256) void k_norm(
    float* __restrict__ attn, const float* __restrict__ wsum_tot){
  size_t i = (size_t)blockIdx.x*256 + threadIdx.x;
  int s = (int)(i % 7);
  int b = (int)(i / (NSEQ*7));
  attn[i] = attn[i] / wsum_tot[b*7 + s];
}

// ---------------- launch ----------------
extern "C" void kernel_launch(void* const* d_in, const int* in_sizes, int n_in,
                              void* d_out, int out_size, void* d_ws, size_t ws_size,
                              hipStream_t stream){
  (void)in_sizes; (void)n_in; (void)out_size; (void)ws_size;
  const float* inputs  = (const float*)d_in[0];
  const float* noise   = (const float*)d_in[1];
  const float* ln_in_g = (const float*)d_in[2];
  const float* ln_in_b = (const float*)d_in[3];
  const float* ln_sl_g = (const float*)d_in[4];
  const float* ln_sl_b = (const float*)d_in[5];
  const float* ln_ml_g = (const float*)d_in[6];
  const float* ln_ml_b = (const float*)d_in[7];
  const float* mu      = (const float*)d_in[8];
  const float* sig     = (const float*)d_in[9];
  const float* wq      = (const float*)d_in[10];
  const float* bq      = (const float*)d_in[11];
  const float* wk      = (const float*)d_in[12];
  const float* bk      = (const float*)d_in[13];
  const float* wv      = (const float*)d_in[14];
  const float* bv      = (const float*)d_in[15];
  const float* w_ih    = (const float*)d_in[16];
  const float* b_ih    = (const float*)d_in[17];
  const float* w_hh    = (const float*)d_in[18];
  const float* b_hh    = (const float*)d_in[19];
  const float* w1      = (const float*)d_in[20];
  const float* b1      = (const float*)d_in[21];
  const float* w2      = (const float*)d_in[22];
  const float* b2      = (const float*)d_in[23];

  char* ws = (char*)d_ws;
  u16*   x_bf   = (u16*)(ws);                         // 67108864 B
  u16*   kv     = (u16*)(ws + 67108864);              // 134217728 B
  float* pacc   = (float*)(ws + 201326592);           // 7340032 B
  u16*   Wkv    = (u16*)(ws + 208666624);             // 262144 B
  float* qeff   = (float*)(ws + 208928768);           // 229376 B
  float* slots  = (float*)(ws + 209158144);           // 229376 B
  float* pw     = (float*)(ws + 209387520);           // 28672 B
  float* biaskv = (float*)(ws + 209416192);           // 2048 B
  float* wsum   = (float*)(ws + 209418240);           // 896 B

  float* out_slots = (float*)d_out;
  float* attn = (float*)d_out + 57344;

  k_prep<<<737, 256, 0, stream>>>(wk, wv, bk, bv, mu, sig, noise, Wkv, biaskv, slots);
  k_ln_in<<<32768, 256, 0, stream>>>(inputs, ln_in_g, ln_in_b, x_bf);
  k_gemm_kv<<<dim3(4, 1024), 256, 0, stream>>>(x_bf, Wkv, biaskv, kv);
  for (int i = 0; i < 3; ++i){
    k_qproj<<<224, 256, 0, stream>>>(slots, ln_sl_g, ln_sl_b, wq, bq, qeff);
    k_attn<<<dim3(32, 32), 256, 0, stream>>>(kv, qeff, attn, pacc, pw);
    k_slot<<<224, 768, 0, stream>>>(pacc, pw, slots, w_ih, b_ih, w_hh, b_hh,
                                    ln_ml_g, ln_ml_b, w1, b1, w2, b2,
                                    wsum, out_slots, (i == 2) ? 1 : 0);
  }
  k_norm<<<3584, 256, 0, stream>>>(attn, wsum);
}

// Round 3
// 431.631 us; speedup vs baseline: 1.5595x; 1.5595x over previous
//
#include <hip/hip_runtime.h>
#include <stdint.h>

typedef unsigned short u16;
typedef unsigned int u32;
typedef float f32x4 __attribute__((ext_vector_type(4)));
typedef short short8 __attribute__((ext_vector_type(8)));

#define NBAT 32
#define NSEQ 4096
#define ND 256
#define NSLOT 7

// ---------------- helpers ----------------
__device__ __forceinline__ u32 bf16rne(float f){
  u32 u = __float_as_uint(f);
  u = u + 0x7FFFu + ((u >> 16) & 1u);
  return u >> 16;
}
__device__ __forceinline__ u32 packbf(float a, float b){
  return (bf16rne(a) & 0xFFFFu) | (bf16rne(b) << 16);
}
__device__ __forceinline__ float bflo(u32 u){ return __uint_as_float(u << 16); }
__device__ __forceinline__ float bfhi(u32 u){ return __uint_as_float(u & 0xFFFF0000u); }

__device__ __forceinline__ void gld16(void* lds, const void* g){
  __builtin_amdgcn_global_load_lds(
      (const __attribute__((address_space(1))) u32*)g,
      (__attribute__((address_space(3))) u32*)lds, 16, 0, 0);
}

__device__ __forceinline__ void softmax7(const float* z, float* p){
  float m = fmaxf(fmaxf(fmaxf(z[0], z[1]), fmaxf(z[2], z[3])),
                  fmaxf(fmaxf(z[4], z[5]), z[6]));
  float sum = 0.f;
#pragma unroll
  for (int s = 0; s < 7; ++s){ p[s] = exp2f(z[s] - m); sum += p[s]; }
  float r = 1.f / sum;
#pragma unroll
  for (int s = 0; s < 7; ++s) p[s] = fmaf(p[s], r, 1e-8f);
}

// ---------------- prep: bf16 weight copies, bias concat, slots init ----------------
__global__ __launch_bounds__(256) void k_prep(
    const float* __restrict__ wk, const float* __restrict__ wv,
    const float* __restrict__ bk, const float* __restrict__ bv,
    const float* __restrict__ mu, const float* __restrict__ sig,
    const float* __restrict__ noise,
    const float* __restrict__ w_ih, const float* __restrict__ b_ih,
    const float* __restrict__ w_hh, const float* __restrict__ b_hh,
    const float* __restrict__ w1, const float* __restrict__ w2,
    const float* __restrict__ wq,
    u16* __restrict__ Wkv, float* __restrict__ biaskv, float* __restrict__ slots,
    u16* __restrict__ Wg, u16* __restrict__ w1b, u16* __restrict__ w2b,
    u16* __restrict__ wqb, float* __restrict__ bg){
  const int bid = blockIdx.x, t = threadIdx.x;
  if (bid < 512){
    const float* src = (bid < 256) ? (wk + (size_t)bid*256) : (wv + (size_t)(bid-256)*256);
    Wkv[(size_t)bid*256 + t] = (u16)bf16rne(src[t]);
  } else if (bid == 512){
    biaskv[t] = bk[t];
    biaskv[256 + t] = bv[t];
  } else if (bid < 737){
    int r = bid - 513; // 0..223
    float sp = logf(1.f + expf(sig[t]));   // softplus
    slots[(size_t)r*256 + t] = mu[t] + sp * noise[(size_t)r*256 + t];
  } else if (bid < 1761){
    // Wg[1024][512]: rows 0-511 = [wih|whh]; 512-767 = [wih_n|0]; 768-1023 = [0|whh_n]
    int j = bid - 737;
    u16 a, b;
    if (j < 512){ a = (u16)bf16rne(w_ih[(size_t)j*256 + t]); b = (u16)bf16rne(w_hh[(size_t)j*256 + t]); }
    else if (j < 768){ a = (u16)bf16rne(w_ih[(size_t)j*256 + t]); b = 0; }
    else { a = 0; b = (u16)bf16rne(w_hh[(size_t)(j-256)*256 + t]); }
    Wg[(size_t)j*512 + t] = a;
    Wg[(size_t)j*512 + 256 + t] = b;
  } else if (bid < 2273){
    int j = bid - 1761; // 0..511
    w1b[(size_t)j*256 + t] = (u16)bf16rne(w1[(size_t)j*256 + t]);
  } else if (bid < 2529){
    int j = bid - 2273; // 0..255
    w2b[(size_t)j*512 + t]       = (u16)bf16rne(w2[(size_t)j*512 + t]);
    w2b[(size_t)j*512 + 256 + t] = (u16)bf16rne(w2[(size_t)j*512 + 256 + t]);
  } else if (bid < 2785){
    int j = bid - 2529; // 0..255
    wqb[(size_t)j*256 + t] = (u16)bf16rne(wq[(size_t)j*256 + t]);
  } else {
#pragma unroll
    for (int ii = 0; ii < 4; ++ii){
      int j = ii*256 + t;
      float v;
      if (j < 512) v = b_ih[j] + b_hh[j];
      else if (j < 768) v = b_ih[j];
      else v = b_hh[j - 256];
      bg[j] = v;
    }
  }
}

// ---------------- K1: LayerNorm(inputs) -> x bf16, one wave per row ----------------
__global__ __launch_bounds__(256) void k_ln_in(
    const float* __restrict__ x, const float* __restrict__ g, const float* __restrict__ b,
    u16* __restrict__ xo){
  const int row = blockIdx.x*4 + (threadIdx.x >> 6);
  const int lane = threadIdx.x & 63;
  const f32x4 v = *(const f32x4*)(x + (size_t)row*ND + lane*4);
  float s  = v[0]+v[1]+v[2]+v[3];
  float s2 = v[0]*v[0]+v[1]*v[1]+v[2]*v[2]+v[3]*v[3];
#pragma unroll
  for (int m = 1; m < 64; m <<= 1){ s += __shfl_xor(s, m); s2 += __shfl_xor(s2, m); }
  const float mean = s * (1.f/256.f);
  const float var  = s2 * (1.f/256.f) - mean*mean;
  const float rstd = rsqrtf(var + 1e-5f);
  const f32x4 gg = *(const f32x4*)(g + lane*4);
  const f32x4 bb = *(const f32x4*)(b + lane*4);
  float y0 = (v[0]-mean)*rstd*gg[0] + bb[0];
  float y1 = (v[1]-mean)*rstd*gg[1] + bb[1];
  float y2 = (v[2]-mean)*rstd*gg[2] + bb[2];
  float y3 = (v[3]-mean)*rstd*gg[3] + bb[3];
  uint2 o; o.x = packbf(y0, y1); o.y = packbf(y2, y3);
  *(uint2*)(xo + (size_t)row*ND + lane*4) = o;
}

// ---------------- K2: kv = x @ Wkv^T + bias  (MFMA bf16, 128x128 tile, BK=64) ----------------
__global__ __launch_bounds__(256) void k_gemm_kv(
    const u16* __restrict__ X, const u16* __restrict__ W,
    const float* __restrict__ biaskv, u16* __restrict__ kv){
  __shared__ __align__(16) u16 At[128*64];
  __shared__ __align__(16) u16 Bt[128*64];
  const int nb = blockIdx.x, mb = blockIdx.y;
  const int tid = threadIdx.x, w = tid >> 6, lane = tid & 63;
  const int wm = w >> 1, wn = w & 1;
  f32x4 acc[4][4];
#pragma unroll
  for (int a = 0; a < 4; ++a)
#pragma unroll
    for (int c = 0; c < 4; ++c) acc[a][c] = (f32x4){0.f,0.f,0.f,0.f};

  const int cl = lane & 7;
  for (int kt = 0; kt < 4; ++kt){
#pragma unroll
    for (int i = 0; i < 4; ++i){
      int R = w*32 + i*8 + (lane >> 3);
      int c = cl ^ (R & 7);
      gld16(&At[(w*32 + i*8)*64], X + ((size_t)(mb*128 + R))*256 + kt*64 + c*8);
      gld16(&Bt[(w*32 + i*8)*64], W + ((size_t)(nb*128 + R))*256 + kt*64 + c*8);
    }
    __syncthreads();
#pragma unroll
    for (int kk = 0; kk < 2; ++kk){
      short8 xf[4], wf[4];
#pragma unroll
      for (int xi = 0; xi < 4; ++xi){
        int r = wm*64 + xi*16 + (lane & 15);
        int ch = (kk*4 + (lane >> 4)) ^ (r & 7);
        xf[xi] = *(const short8*)&At[r*64 + ch*8];
      }
#pragma unroll
      for (int wi = 0; wi < 4; ++wi){
        int r = wn*64 + wi*16 + (lane & 15);
        int ch = (kk*4 + (lane >> 4)) ^ (r & 7);
        wf[wi] = *(const short8*)&Bt[r*64 + ch*8];
      }
#pragma unroll
      for (int xi = 0; xi < 4; ++xi)
#pragma unroll
        for (int wi = 0; wi < 4; ++wi)
          acc[xi][wi] = __builtin_amdgcn_mfma_f32_16x16x32_bf16(wf[wi], xf[xi], acc[xi][wi], 0, 0, 0);
    }
    __syncthreads();
  }
  f32x4 bias[4];
#pragma unroll
  for (int wi = 0; wi < 4; ++wi)
    bias[wi] = *(const f32x4*)(biaskv + nb*128 + wn*64 + wi*16 + (lane >> 4)*4);
#pragma unroll
  for (int xi = 0; xi < 4; ++xi){
    size_t m = (size_t)mb*128 + wm*64 + xi*16 + (lane & 15);
    u16* dst = kv + m*512 + nb*128 + wn*64 + (lane >> 4)*4;
#pragma unroll
    for (int wi = 0; wi < 4; ++wi){
      f32x4 c = acc[xi][wi];
      uint2 o;
      o.x = packbf(c[0] + bias[wi][0], c[1] + bias[wi][1]);
      o.y = packbf(c[2] + bias[wi][2], c[3] + bias[wi][3]);
      *(uint2*)(dst + wi*16) = o;
    }
  }
}

// ---------------- small-GEMM (MFMA, 128x128 tile): out = A @ W^T + bias, MODE epilogues ----
// MODE 0: gates, f32 out ld=1024
// MODE 1: mlp1, relu -> bf16 out ld=512
// MODE 2: mlp2, + snew + bias -> slots f32 ld=256 (rows<224), optional out_slots copy
// MODE 3: qproj, (acc+bias)*log2(e)/16 -> f32 ld=256
template<int MODE>
__global__ __launch_bounds__(256) void k_gemm_s(
    const u16* __restrict__ A, const u16* __restrict__ W,
    const float* __restrict__ bias, int nkt,
    float* __restrict__ outf, u16* __restrict__ outb,
    const float* __restrict__ snew, float* __restrict__ out2, int last){
  __shared__ __align__(16) u16 At[128*64];
  __shared__ __align__(16) u16 Bt[128*64];
  const int nb = blockIdx.x, mb = blockIdx.y;
  const int tid = threadIdx.x, w = tid >> 6, lane = tid & 63;
  const int wm = w >> 1, wn = w & 1;
  const size_t K = (size_t)nkt * 64;
  f32x4 acc[4][4];
#pragma unroll
  for (int a = 0; a < 4; ++a)
#pragma unroll
    for (int c = 0; c < 4; ++c) acc[a][c] = (f32x4){0.f,0.f,0.f,0.f};

  const int cl = lane & 7;
  for (int kt = 0; kt < nkt; ++kt){
#pragma unroll
    for (int i = 0; i < 4; ++i){
      int R = w*32 + i*8 + (lane >> 3);
      int c = cl ^ (R & 7);
      gld16(&At[(w*32 + i*8)*64], A + ((size_t)(mb*128 + R))*K + kt*64 + c*8);
      gld16(&Bt[(w*32 + i*8)*64], W + ((size_t)(nb*128 + R))*K + kt*64 + c*8);
    }
    __syncthreads();
#pragma unroll
    for (int kk = 0; kk < 2; ++kk){
      short8 xf[4], wf[4];
#pragma unroll
      for (int xi = 0; xi < 4; ++xi){
        int r = wm*64 + xi*16 + (lane & 15);
        int ch = (kk*4 + (lane >> 4)) ^ (r & 7);
        xf[xi] = *(const short8*)&At[r*64 + ch*8];
      }
#pragma unroll
      for (int wi = 0; wi < 4; ++wi){
        int r = wn*64 + wi*16 + (lane & 15);
        int ch = (kk*4 + (lane >> 4)) ^ (r & 7);
        wf[wi] = *(const short8*)&Bt[r*64 + ch*8];
      }
#pragma unroll
      for (int xi = 0; xi < 4; ++xi)
#pragma unroll
        for (int wi = 0; wi < 4; ++wi)
          acc[xi][wi] = __builtin_amdgcn_mfma_f32_16x16x32_bf16(wf[wi], xf[xi], acc[xi][wi], 0, 0, 0);
    }
    __syncthreads();
  }
  const int LDO = (MODE == 0) ? 1024 : ((MODE == 1) ? 512 : 256);
  f32x4 b4[4];
#pragma unroll
  for (int wi = 0; wi < 4; ++wi)
    b4[wi] = *(const f32x4*)(bias + nb*128 + wn*64 + wi*16 + (lane >> 4)*4);
#pragma unroll
  for (int xi = 0; xi < 4; ++xi){
    const int m = mb*128 + wm*64 + xi*16 + (lane & 15);
    const int colb = nb*128 + wn*64 + (lane >> 4)*4;
#pragma unroll
    for (int wi = 0; wi < 4; ++wi){
      const int col = colb + wi*16;
      f32x4 c = acc[xi][wi] + b4[wi];
      if (MODE == 0){
        *(f32x4*)(outf + (size_t)m*LDO + col) = c;
      } else if (MODE == 1){
        uint2 o;
        o.x = packbf(fmaxf(c[0],0.f), fmaxf(c[1],0.f));
        o.y = packbf(fmaxf(c[2],0.f), fmaxf(c[3],0.f));
        *(uint2*)(outb + (size_t)m*LDO + col) = o;
      } else if (MODE == 2){
        if (m < 224){
          const f32x4 s4 = *(const f32x4*)(snew + (size_t)m*256 + col);
          f32x4 o = c + s4;
          *(f32x4*)(outf + (size_t)m*LDO + col) = o;
          if (last) *(f32x4*)(out2 + (size_t)m*LDO + col) = o;
        }
      } else { // MODE 3
        f32x4 o = c * 0.09016844f; // log2(e)/16
        *(f32x4*)(outf + (size_t)m*LDO + col) = o;
      }
    }
  }
}

// ---------------- K4: fused logits -> softmax(S) -> partial (p'@v, sum p') ----------------
__global__ __launch_bounds__(256) void k_attn(
    const u16* __restrict__ kv, const float* __restrict__ qeff,
    float* __restrict__ attn_out, float* __restrict__ pacc, float* __restrict__ pw){
  __shared__ __align__(16) float accbuf[4][7][256];
  __shared__ float wsbuf[4][7];
  const int chunk = blockIdx.x, b = blockIdx.y;
  const int tid = threadIdx.x, w = tid >> 6, lane = tid & 63, hi = lane >> 5, lo = lane & 31;
  float qr[7][8];
  {
    const float* qb = qeff + (size_t)b*(NSLOT*256) + lo*8;
#pragma unroll
    for (int s = 0; s < 7; ++s){
      f32x4 q0 = *(const f32x4*)(qb + s*256);
      f32x4 q1 = *(const f32x4*)(qb + s*256 + 4);
      qr[s][0]=q0[0]; qr[s][1]=q0[1]; qr[s][2]=q0[2]; qr[s][3]=q0[3];
      qr[s][4]=q1[0]; qr[s][5]=q1[1]; qr[s][6]=q1[2]; qr[s][7]=q1[3];
    }
  }
  float acc[7][4]; float wsm[7];
#pragma unroll
  for (int s = 0; s < 7; ++s){ acc[s][0]=acc[s][1]=acc[s][2]=acc[s][3]=0.f; wsm[s]=0.f; }

  const size_t bbase = (size_t)b*NSEQ;
  for (int it = 0; it < 16; ++it){
    const int nr = chunk*128 + it*8 + w*2;
    const size_t rowm = (bbase + nr + hi)*512;
    const size_t rowo = (bbase + nr + (1 - hi))*512;
    uint4 k4 = *(const uint4*)(kv + rowm + lo*8);
    float kf[8];
    kf[0]=bflo(k4.x); kf[1]=bfhi(k4.x); kf[2]=bflo(k4.y); kf[3]=bfhi(k4.y);
    kf[4]=bflo(k4.z); kf[5]=bfhi(k4.z); kf[6]=bflo(k4.w); kf[7]=bfhi(k4.w);
    float z[7];
#pragma unroll
    for (int s = 0; s < 7; ++s){
      float d0 = fmaf(qr[s][0],kf[0], fmaf(qr[s][1],kf[1], fmaf(qr[s][2],kf[2], qr[s][3]*kf[3])));
      float d1 = fmaf(qr[s][4],kf[4], fmaf(qr[s][5],kf[5], fmaf(qr[s][6],kf[6], qr[s][7]*kf[7])));
      z[s] = d0 + d1;
    }
#pragma unroll
    for (int m = 1; m < 32; m <<= 1){
#pragma unroll
      for (int s = 0; s < 7; ++s) z[s] += __shfl_xor(z[s], m);
    }
    float zo[7];
#pragma unroll
    for (int s = 0; s < 7; ++s) zo[s] = __shfl_xor(z[s], 32);
    float pm[7], po[7];
    softmax7(z, pm);
    softmax7(zo, po);
    float sel = pm[0];
    sel = (lo==1)?pm[1]:sel; sel = (lo==2)?pm[2]:sel; sel = (lo==3)?pm[3]:sel;
    sel = (lo==4)?pm[4]:sel; sel = (lo==5)?pm[5]:sel; sel = (lo==6)?pm[6]:sel;
    if (lo < 7) attn_out[(bbase + nr + hi)*7 + lo] = sel;
    uint2 va = *(const uint2*)(kv + rowm + 256 + (size_t)lane*4);
    uint2 vb = *(const uint2*)(kv + rowo + 256 + (size_t)lane*4);
    float vm0=bflo(va.x), vm1=bfhi(va.x), vm2=bflo(va.y), vm3=bfhi(va.y);
    float vo0=bflo(vb.x), vo1=bfhi(vb.x), vo2=bflo(vb.y), vo3=bfhi(vb.y);
#pragma unroll
    for (int s = 0; s < 7; ++s){
      acc[s][0] = fmaf(pm[s], vm0, fmaf(po[s], vo0, acc[s][0]));
      acc[s][1] = fmaf(pm[s], vm1, fmaf(po[s], vo1, acc[s][1]));
      acc[s][2] = fmaf(pm[s], vm2, fmaf(po[s], vo2, acc[s][2]));
      acc[s][3] = fmaf(pm[s], vm3, fmaf(po[s], vo3, acc[s][3]));
      wsm[s] += pm[s] + po[s];
    }
  }
#pragma unroll
  for (int s = 0; s < 7; ++s)
    *(f32x4*)&accbuf[w][s][lane*4] = (f32x4){acc[s][0], acc[s][1], acc[s][2], acc[s][3]};
  if (lane == 0){
#pragma unroll
    for (int s = 0; s < 7; ++s) wsbuf[w][s] = wsm[s];
  }
  __syncthreads();
#pragma unroll
  for (int s = 0; s < 7; ++s){
    float sum = accbuf[0][s][tid] + accbuf[1][s][tid] + accbuf[2][s][tid] + accbuf[3][s][tid];
    pacc[((size_t)chunk*NBAT + b)*(NSLOT*256) + s*256 + tid] = sum;
  }
  if (tid < 7)
    pw[((size_t)chunk*NBAT + b)*NSLOT + tid] =
        wsbuf[0][tid] + wsbuf[1][tid] + wsbuf[2][tid] + wsbuf[3][tid];
}

// ---------------- slotA: reduce pacc -> A2 = [bf16(updates) | bf16(slots_prev)] ----------------
__global__ __launch_bounds__(256) void k_slotA(
    const float* __restrict__ pacc, const float* __restrict__ pw,
    const float* __restrict__ slots, u16* __restrict__ A2, float* __restrict__ wsum){
  __shared__ float pwb[32];
  const int r = blockIdx.x, t = threadIdx.x;
  if (r >= 224){
    A2[(size_t)r*512 + t] = 0;
    A2[(size_t)r*512 + 256 + t] = 0;
    return;
  }
  if (t < 32) pwb[t] = pw[(size_t)t*224 + r];
  float u = 0.f;
#pragma unroll 8
  for (int c = 0; c < 32; ++c) u += pacc[(size_t)c*57344 + (size_t)r*256 + t];
  __syncthreads();
  float wst = 0.f;
#pragma unroll
  for (int c = 0; c < 32; ++c) wst += pwb[c];
  if (t == 0) wsum[r] = wst;
  A2[(size_t)r*512 + t] = (u16)bf16rne(u / wst);
  A2[(size_t)r*512 + 256 + t] = (u16)bf16rne(slots[(size_t)r*256 + t]);
}

// ---------------- slotB: GRU elementwise + LN -> lnm bf16, snew f32 ----------------
__global__ __launch_bounds__(256) void k_slotB(
    const float* __restrict__ gates, const float* __restrict__ slots,
    const float* __restrict__ gm, const float* __restrict__ bm,
    float* __restrict__ snew, u16* __restrict__ lnm){
  __shared__ float red[8];
  const int r = blockIdx.x, t = threadIdx.x;
  if (r >= 224){ lnm[(size_t)r*256 + t] = 0; return; }
  const float g0  = gates[(size_t)r*1024 + t];
  const float g1  = gates[(size_t)r*1024 + 256 + t];
  const float gin = gates[(size_t)r*1024 + 512 + t];
  const float ghn = gates[(size_t)r*1024 + 768 + t];
  const float spv = slots[(size_t)r*256 + t];
  const float rr = 1.f/(1.f + __expf(-g0));
  const float zz = 1.f/(1.f + __expf(-g1));
  float xx = gin + rr*ghn;
  xx = fminf(fmaxf(xx, -15.f), 15.f);
  const float e2 = __expf(2.f*xx);
  const float nn = (e2 - 1.f)/(e2 + 1.f);
  const float sp = (1.f - zz)*nn + zz*spv;
  snew[(size_t)r*256 + t] = sp;
  float s = sp, s2 = sp*sp;
#pragma unroll
  for (int m = 1; m < 64; m <<= 1){ s += __shfl_xor(s, m); s2 += __shfl_xor(s2, m); }
  if ((t & 63) == 0){ red[t >> 6] = s; red[4 + (t >> 6)] = s2; }
  __syncthreads();
  const float ssum = red[0]+red[1]+red[2]+red[3];
  const float qsum = red[4]+red[5]+red[6]+red[7];
  const float mean = ssum*(1.f/256.f);
  const float var  = qsum*(1.f/256.f) - mean*mean;
  const float rstd = rsqrtf(var + 1e-5f);
  lnm[(size_t)r*256 + t] = (u16)bf16rne((sp - mean)*rstd*gm[t] + bm[t]);
}

// ---------------- lnq: LN(slots) -> lnq bf16 ----------------
__global__ __launch_bounds__(256) void k_lnq(
    const float* __restrict__ slots, const float* __restrict__ g, const float* __restrict__ b,
    u16* __restrict__ lnq){
  __shared__ float red[8];
  const int r = blockIdx.x, t = threadIdx.x;
  if (r >= 224){ lnq[(size_t)r*256 + t] = 0; return; }
  const float x = slots[(size_t)r*256 + t];
  float s = x, s2 = x*x;
#pragma unroll
  for (int m = 1; m < 64; m <<= 1){ s += __shfl_xor(s, m); s2 += __shfl_xor(s2, m); }
  if ((t & 63) == 0){ red[t >> 6] = s; red[4 + (t >> 6)] = s2; }
  __syncthreads();
  const float ssum = red[0]+red[1]+red[2]+red[3];
  const float qsum = red[4]+red[5]+red[6]+red[7];
  const float mean = ssum*(1.f/256.f);
  const float var  = qsum*(1.f/256.f) - mean*mean;
  const float rstd = rsqrtf(var + 1e-5f);
  lnq[(size_t)r*256 + t] = (u16)bf16rne((x - mean)*rstd*g[t] + b[t]);
}

// ---------------- K6: attn /= sum over n ----------------
__global__ __launch_bounds__(256) void k_norm(
    float* __restrict__ attn, const float* __restrict__ wsum_tot){
  size_t i = (size_t)blockIdx.x*256 + threadIdx.x;
  int s = (int)(i % 7);
  int b = (int)(i / (NSEQ*7));
  attn[i] = attn[i] / wsum_tot[b*7 + s];
}

// ---------------- launch ----------------
extern "C" void kernel_launch(void* const* d_in, const int* in_sizes, int n_in,
                              void* d_out, int out_size, void* d_ws, size_t ws_size,
                              hipStream_t stream){
  (void)in_sizes; (void)n_in; (void)out_size; (void)ws_size;
  const float* inputs  = (const float*)d_in[0];
  const float* noise   = (const float*)d_in[1];
  const float* ln_in_g = (const float*)d_in[2];
  const float* ln_in_b = (const float*)d_in[3];
  const float* ln_sl_g = (const float*)d_in[4];
  const float* ln_sl_b = (const float*)d_in[5];
  const float* ln_ml_g = (const float*)d_in[6];
  const float* ln_ml_b = (const float*)d_in[7];
  const float* mu      = (const float*)d_in[8];
  const float* sig     = (const float*)d_in[9];
  const float* wq      = (const float*)d_in[10];
  const float* bq      = (const float*)d_in[11];
  const float* wk      = (const float*)d_in[12];
  const float* bk      = (const float*)d_in[13];
  const float* wv      = (const float*)d_in[14];
  const float* bv      = (const float*)d_in[15];
  const float* w_ih    = (const float*)d_in[16];
  const float* b_ih    = (const float*)d_in[17];
  const float* w_hh    = (const float*)d_in[18];
  const float* b_hh    = (const float*)d_in[19];
  const float* w1      = (const float*)d_in[20];
  const float* b1      = (const float*)d_in[21];
  const float* w2      = (const float*)d_in[22];
  const float* b2      = (const float*)d_in[23];

  char* ws = (char*)d_ws;
  u16*   x_bf   = (u16*)(ws);                         // 67108864
  u16*   kv     = (u16*)(ws + 67108864);              // 134217728
  char*  paccch = ws + 201326592;                     // 7340032 (pacc + aliased transients)
  float* pacc   = (float*)paccch;
  u16*   Wkv    = (u16*)(ws + 208666624);             // 262144
  float* qeff   = (float*)(ws + 208928768);           // 262144 (256 rows)
  float* slots  = (float*)(ws + 209190912);           // 229376
  float* pw     = (float*)(ws + 209420288);           // 28672
  float* biaskv = (float*)(ws + 209448960);           // 2048
  float* wsum   = (float*)(ws + 209451008);           // 1024
  u16*   A2     = (u16*)(ws + 209452032);             // 262144
  u16*   Wg     = (u16*)(ws + 209714176);             // 1048576
  u16*   w1b    = (u16*)(ws + 210762752);             // 262144
  u16*   w2b    = (u16*)(ws + 211024896);             // 262144
  u16*   wqb    = (u16*)(ws + 211287040);             // 131072
  float* bg     = (float*)(ws + 211418112);           // 4096

  // transients aliased into pacc region (pacc dead between k_slotA and next k_attn)
  float* gates  = (float*)(paccch);                   // 1048576
  u16*   hb     = (u16*)(paccch + 1048576);           // 262144
  u16*   lnm    = (u16*)(paccch + 1310720);           // 131072
  u16*   lnq    = (u16*)(paccch + 1441792);           // 131072
  float* snew   = (float*)(paccch + 1572864);         // 229376

  float* out_slots = (float*)d_out;
  float* attn = (float*)d_out + 57344;

  k_prep<<<2786, 256, 0, stream>>>(wk, wv, bk, bv, mu, sig, noise,
                                   w_ih, b_ih, w_hh, b_hh, w1, w2, wq,
                                   Wkv, biaskv, slots, Wg, w1b, w2b, wqb, bg);
  k_ln_in<<<32768, 256, 0, stream>>>(inputs, ln_in_g, ln_in_b, x_bf);
  k_gemm_kv<<<dim3(4, 1024), 256, 0, stream>>>(x_bf, Wkv, biaskv, kv);
  for (int i = 0; i < 3; ++i){
    const int last = (i == 2) ? 1 : 0;
    k_lnq<<<256, 256, 0, stream>>>(slots, ln_sl_g, ln_sl_b, lnq);
    k_gemm_s<3><<<dim3(2, 2), 256, 0, stream>>>(lnq, wqb, bq, 4, qeff, nullptr, nullptr, nullptr, 0);
    k_attn<<<dim3(32, 32), 256, 0, stream>>>(kv, qeff, attn, pacc, pw);
    k_slotA<<<256, 256, 0, stream>>>(pacc, pw, slots, A2, wsum);
    k_gemm_s<0><<<dim3(8, 2), 256, 0, stream>>>(A2, Wg, bg, 8, gates, nullptr, nullptr, nullptr, 0);
    k_slotB<<<256, 256, 0, stream>>>(gates, slots, ln_ml_g, ln_ml_b, snew, lnm);
    k_gemm_s<1><<<dim3(4, 2), 256, 0, stream>>>(lnm, w1b, b1, 4, nullptr, hb, nullptr, nullptr, 0);
    k_gemm_s<2><<<dim3(2, 2), 256, 0, stream>>>(hb, w2b, b2, 8, slots, nullptr, snew, out_slots, last);
  }
  k_norm<<<3584, 256, 0, stream>>>(attn, wsum);
}

// Round 4
// 417.187 us; speedup vs baseline: 1.6134x; 1.0346x over previous
//
#include <hip/hip_runtime.h>
#include <stdint.h>

typedef unsigned short u16;
typedef unsigned int u32;
typedef float f32x4 __attribute__((ext_vector_type(4)));
typedef short short8 __attribute__((ext_vector_type(8)));

#define NBAT 32
#define NSEQ 4096
#define ND 256
#define NSLOT 7
#define NCHUNK 64

// ---------------- helpers ----------------
__device__ __forceinline__ u32 bf16rne(float f){
  u32 u = __float_as_uint(f);
  u = u + 0x7FFFu + ((u >> 16) & 1u);
  return u >> 16;
}
__device__ __forceinline__ u32 packbf(float a, float b){
  return (bf16rne(a) & 0xFFFFu) | (bf16rne(b) << 16);
}
__device__ __forceinline__ float bflo(u32 u){ return __uint_as_float(u << 16); }
__device__ __forceinline__ float bfhi(u32 u){ return __uint_as_float(u & 0xFFFF0000u); }

__device__ __forceinline__ void gld16(void* lds, const void* g){
  __builtin_amdgcn_global_load_lds(
      (const __attribute__((address_space(1))) u32*)g,
      (__attribute__((address_space(3))) u32*)lds, 16, 0, 0);
}

__device__ __forceinline__ void softmax7(const float* z, float* p){
  float m = fmaxf(fmaxf(fmaxf(z[0], z[1]), fmaxf(z[2], z[3])),
                  fmaxf(fmaxf(z[4], z[5]), z[6]));
  float sum = 0.f;
#pragma unroll
  for (int s = 0; s < 7; ++s){ p[s] = exp2f(z[s] - m); sum += p[s]; }
  float r = 1.f / sum;
#pragma unroll
  for (int s = 0; s < 7; ++s) p[s] = fmaf(p[s], r, 1e-8f);
}

// ---------------- prep: bf16 weight copies, bias concat, slots init ----------------
__global__ __launch_bounds__(256) void k_prep(
    const float* __restrict__ wk, const float* __restrict__ wv,
    const float* __restrict__ bk, const float* __restrict__ bv,
    const float* __restrict__ mu, const float* __restrict__ sig,
    const float* __restrict__ noise,
    const float* __restrict__ w_ih, const float* __restrict__ b_ih,
    const float* __restrict__ w_hh, const float* __restrict__ b_hh,
    const float* __restrict__ w1, const float* __restrict__ w2,
    const float* __restrict__ wq,
    u16* __restrict__ Wkv, float* __restrict__ biaskv, float* __restrict__ slots,
    u16* __restrict__ Wg, u16* __restrict__ w1b, u16* __restrict__ w2b,
    u16* __restrict__ wqb, float* __restrict__ bg){
  const int bid = blockIdx.x, t = threadIdx.x;
  if (bid < 512){
    const float* src = (bid < 256) ? (wk + (size_t)bid*256) : (wv + (size_t)(bid-256)*256);
    Wkv[(size_t)bid*256 + t] = (u16)bf16rne(src[t]);
  } else if (bid == 512){
    biaskv[t] = bk[t];
    biaskv[256 + t] = bv[t];
  } else if (bid < 737){
    int r = bid - 513; // 0..223
    float sp = logf(1.f + expf(sig[t]));   // softplus
    slots[(size_t)r*256 + t] = mu[t] + sp * noise[(size_t)r*256 + t];
  } else if (bid < 1761){
    // Wg[1024][512]: rows 0-511 = [wih|whh]; 512-767 = [wih_n|0]; 768-1023 = [0|whh_n]
    int j = bid - 737;
    u16 a, b;
    if (j < 512){ a = (u16)bf16rne(w_ih[(size_t)j*256 + t]); b = (u16)bf16rne(w_hh[(size_t)j*256 + t]); }
    else if (j < 768){ a = (u16)bf16rne(w_ih[(size_t)j*256 + t]); b = 0; }
    else { a = 0; b = (u16)bf16rne(w_hh[(size_t)(j-256)*256 + t]); }
    Wg[(size_t)j*512 + t] = a;
    Wg[(size_t)j*512 + 256 + t] = b;
  } else if (bid < 2273){
    int j = bid - 1761; // 0..511
    w1b[(size_t)j*256 + t] = (u16)bf16rne(w1[(size_t)j*256 + t]);
  } else if (bid < 2529){
    int j = bid - 2273; // 0..255
    w2b[(size_t)j*512 + t]       = (u16)bf16rne(w2[(size_t)j*512 + t]);
    w2b[(size_t)j*512 + 256 + t] = (u16)bf16rne(w2[(size_t)j*512 + 256 + t]);
  } else if (bid < 2785){
    int j = bid - 2529; // 0..255
    wqb[(size_t)j*256 + t] = (u16)bf16rne(wq[(size_t)j*256 + t]);
  } else {
#pragma unroll
    for (int ii = 0; ii < 4; ++ii){
      int j = ii*256 + t;
      float v;
      if (j < 512) v = b_ih[j] + b_hh[j];
      else if (j < 768) v = b_ih[j];
      else v = b_hh[j - 256];
      bg[j] = v;
    }
  }
}

// ---------------- K1: LayerNorm(inputs) -> x bf16, one wave per row ----------------
__global__ __launch_bounds__(256) void k_ln_in(
    const float* __restrict__ x, const float* __restrict__ g, const float* __restrict__ b,
    u16* __restrict__ xo){
  const int row = blockIdx.x*4 + (threadIdx.x >> 6);
  const int lane = threadIdx.x & 63;
  const f32x4 v = *(const f32x4*)(x + (size_t)row*ND + lane*4);
  float s  = v[0]+v[1]+v[2]+v[3];
  float s2 = v[0]*v[0]+v[1]*v[1]+v[2]*v[2]+v[3]*v[3];
#pragma unroll
  for (int m = 1; m < 64; m <<= 1){ s += __shfl_xor(s, m); s2 += __shfl_xor(s2, m); }
  const float mean = s * (1.f/256.f);
  const float var  = s2 * (1.f/256.f) - mean*mean;
  const float rstd = rsqrtf(var + 1e-5f);
  const f32x4 gg = *(const f32x4*)(g + lane*4);
  const f32x4 bb = *(const f32x4*)(b + lane*4);
  float y0 = (v[0]-mean)*rstd*gg[0] + bb[0];
  float y1 = (v[1]-mean)*rstd*gg[1] + bb[1];
  float y2 = (v[2]-mean)*rstd*gg[2] + bb[2];
  float y3 = (v[3]-mean)*rstd*gg[3] + bb[3];
  uint2 o; o.x = packbf(y0, y1); o.y = packbf(y2, y3);
  *(uint2*)(xo + (size_t)row*ND + lane*4) = o;
}

// ---------------- K2: kv = x @ Wkv^T + bias (MFMA bf16, 128x128 tile, XCD swizzle) ----------
__global__ __launch_bounds__(256) void k_gemm_kv(
    const u16* __restrict__ X, const u16* __restrict__ W,
    const float* __restrict__ biaskv, u16* __restrict__ kv){
  __shared__ __align__(16) u16 At[128*64];
  __shared__ __align__(16) u16 Bt[128*64];
  // bijective XCD swizzle: XCD k gets a contiguous mb range; all 4 nb of an mb
  // run back-to-back on the same XCD -> X tile L2-resident, fetched once.
  const int bid = blockIdx.x;                 // 0..4095
  const int swz = ((bid & 7) << 9) + (bid >> 3);
  const int mb = swz >> 2, nb = swz & 3;
  const int tid = threadIdx.x, w = tid >> 6, lane = tid & 63;
  const int wm = w >> 1, wn = w & 1;
  f32x4 acc[4][4];
#pragma unroll
  for (int a = 0; a < 4; ++a)
#pragma unroll
    for (int c = 0; c < 4; ++c) acc[a][c] = (f32x4){0.f,0.f,0.f,0.f};

  const int cl = lane & 7;
  for (int kt = 0; kt < 4; ++kt){
#pragma unroll
    for (int i = 0; i < 4; ++i){
      int R = w*32 + i*8 + (lane >> 3);
      int c = cl ^ (R & 7);
      gld16(&At[(w*32 + i*8)*64], X + ((size_t)(mb*128 + R))*256 + kt*64 + c*8);
      gld16(&Bt[(w*32 + i*8)*64], W + ((size_t)(nb*128 + R))*256 + kt*64 + c*8);
    }
    __syncthreads();
#pragma unroll
    for (int kk = 0; kk < 2; ++kk){
      short8 xf[4], wf[4];
#pragma unroll
      for (int xi = 0; xi < 4; ++xi){
        int r = wm*64 + xi*16 + (lane & 15);
        int ch = (kk*4 + (lane >> 4)) ^ (r & 7);
        xf[xi] = *(const short8*)&At[r*64 + ch*8];
      }
#pragma unroll
      for (int wi = 0; wi < 4; ++wi){
        int r = wn*64 + wi*16 + (lane & 15);
        int ch = (kk*4 + (lane >> 4)) ^ (r & 7);
        wf[wi] = *(const short8*)&Bt[r*64 + ch*8];
      }
#pragma unroll
      for (int xi = 0; xi < 4; ++xi)
#pragma unroll
        for (int wi = 0; wi < 4; ++wi)
          acc[xi][wi] = __builtin_amdgcn_mfma_f32_16x16x32_bf16(wf[wi], xf[xi], acc[xi][wi], 0, 0, 0);
    }
    __syncthreads();
  }
  f32x4 bias[4];
#pragma unroll
  for (int wi = 0; wi < 4; ++wi)
    bias[wi] = *(const f32x4*)(biaskv + nb*128 + wn*64 + wi*16 + (lane >> 4)*4);
#pragma unroll
  for (int xi = 0; xi < 4; ++xi){
    size_t m = (size_t)mb*128 + wm*64 + xi*16 + (lane & 15);
    u16* dst = kv + m*512 + nb*128 + wn*64 + (lane >> 4)*4;
#pragma unroll
    for (int wi = 0; wi < 4; ++wi){
      f32x4 c = acc[xi][wi];
      uint2 o;
      o.x = packbf(c[0] + bias[wi][0], c[1] + bias[wi][1]);
      o.y = packbf(c[2] + bias[wi][2], c[3] + bias[wi][3]);
      *(uint2*)(dst + wi*16) = o;
    }
  }
}

// ---------------- small-GEMM (MFMA, 128x128 tile): out = A @ W^T + bias, MODE epilogues ----
// MODE 0: gates, f32 out ld=1024
// MODE 1: mlp1, relu -> bf16 out ld=512
// MODE 2: mlp2, + snew + bias -> slots f32 ld=256 (rows<224), optional out_slots copy
// MODE 3: qproj, (acc+bias)*log2(e)/16 -> f32 ld=256
template<int MODE>
__global__ __launch_bounds__(256) void k_gemm_s(
    const u16* __restrict__ A, const u16* __restrict__ W,
    const float* __restrict__ bias, int nkt,
    float* __restrict__ outf, u16* __restrict__ outb,
    const float* __restrict__ snew, float* __restrict__ out2, int last){
  __shared__ __align__(16) u16 At[128*64];
  __shared__ __align__(16) u16 Bt[128*64];
  const int nb = blockIdx.x, mb = blockIdx.y;
  const int tid = threadIdx.x, w = tid >> 6, lane = tid & 63;
  const int wm = w >> 1, wn = w & 1;
  const size_t K = (size_t)nkt * 64;
  f32x4 acc[4][4];
#pragma unroll
  for (int a = 0; a < 4; ++a)
#pragma unroll
    for (int c = 0; c < 4; ++c) acc[a][c] = (f32x4){0.f,0.f,0.f,0.f};

  const int cl = lane & 7;
  for (int kt = 0; kt < nkt; ++kt){
#pragma unroll
    for (int i = 0; i < 4; ++i){
      int R = w*32 + i*8 + (lane >> 3);
      int c = cl ^ (R & 7);
      gld16(&At[(w*32 + i*8)*64], A + ((size_t)(mb*128 + R))*K + kt*64 + c*8);
      gld16(&Bt[(w*32 + i*8)*64], W + ((size_t)(nb*128 + R))*K + kt*64 + c*8);
    }
    __syncthreads();
#pragma unroll
    for (int kk = 0; kk < 2; ++kk){
      short8 xf[4], wf[4];
#pragma unroll
      for (int xi = 0; xi < 4; ++xi){
        int r = wm*64 + xi*16 + (lane & 15);
        int ch = (kk*4 + (lane >> 4)) ^ (r & 7);
        xf[xi] = *(const short8*)&At[r*64 + ch*8];
      }
#pragma unroll
      for (int wi = 0; wi < 4; ++wi){
        int r = wn*64 + wi*16 + (lane & 15);
        int ch = (kk*4 + (lane >> 4)) ^ (r & 7);
        wf[wi] = *(const short8*)&Bt[r*64 + ch*8];
      }
#pragma unroll
      for (int xi = 0; xi < 4; ++xi)
#pragma unroll
        for (int wi = 0; wi < 4; ++wi)
          acc[xi][wi] = __builtin_amdgcn_mfma_f32_16x16x32_bf16(wf[wi], xf[xi], acc[xi][wi], 0, 0, 0);
    }
    __syncthreads();
  }
  const int LDO = (MODE == 0) ? 1024 : ((MODE == 1) ? 512 : 256);
  f32x4 b4[4];
#pragma unroll
  for (int wi = 0; wi < 4; ++wi)
    b4[wi] = *(const f32x4*)(bias + nb*128 + wn*64 + wi*16 + (lane >> 4)*4);
#pragma unroll
  for (int xi = 0; xi < 4; ++xi){
    const int m = mb*128 + wm*64 + xi*16 + (lane & 15);
    const int colb = nb*128 + wn*64 + (lane >> 4)*4;
#pragma unroll
    for (int wi = 0; wi < 4; ++wi){
      const int col = colb + wi*16;
      f32x4 c = acc[xi][wi] + b4[wi];
      if (MODE == 0){
        *(f32x4*)(outf + (size_t)m*LDO + col) = c;
      } else if (MODE == 1){
        uint2 o;
        o.x = packbf(fmaxf(c[0],0.f), fmaxf(c[1],0.f));
        o.y = packbf(fmaxf(c[2],0.f), fmaxf(c[3],0.f));
        *(uint2*)(outb + (size_t)m*LDO + col) = o;
      } else if (MODE == 2){
        if (m < 224){
          const f32x4 s4 = *(const f32x4*)(snew + (size_t)m*256 + col);
          f32x4 o = c + s4;
          *(f32x4*)(outf + (size_t)m*LDO + col) = o;
          if (last) *(f32x4*)(out2 + (size_t)m*LDO + col) = o;
        }
      } else { // MODE 3
        f32x4 o = c * 0.09016844f; // log2(e)/16
        *(f32x4*)(outf + (size_t)m*LDO + col) = o;
      }
    }
  }
}

// ---------------- K4: fused logits -> softmax(S) -> partial (p'@v, sum p') ----------------
// 64 chunks x 32 batch = 2048 blocks; 8 iters/block; K/V for it+1 prefetched into
// registers before computing it (hides ~600cy HBM latency under the compute chain).
__global__ __launch_bounds__(256) void k_attn(
    const u16* __restrict__ kv, const float* __restrict__ qeff,
    float* __restrict__ attn_out, float* __restrict__ pacc, float* __restrict__ pw){
  __shared__ __align__(16) float accbuf[4][7][256];
  __shared__ float wsbuf[4][7];
  const int chunk = blockIdx.x, b = blockIdx.y;
  const int tid = threadIdx.x, w = tid >> 6, lane = tid & 63, hi = lane >> 5, lo = lane & 31;
  float qr[7][8];
  {
    const float* qb = qeff + (size_t)b*(NSLOT*256) + lo*8;
#pragma unroll
    for (int s = 0; s < 7; ++s){
      f32x4 q0 = *(const f32x4*)(qb + s*256);
      f32x4 q1 = *(const f32x4*)(qb + s*256 + 4);
      qr[s][0]=q0[0]; qr[s][1]=q0[1]; qr[s][2]=q0[2]; qr[s][3]=q0[3];
      qr[s][4]=q1[0]; qr[s][5]=q1[1]; qr[s][6]=q1[2]; qr[s][7]=q1[3];
    }
  }
  float acc[7][4]; float wsm[7];
#pragma unroll
  for (int s = 0; s < 7; ++s){ acc[s][0]=acc[s][1]=acc[s][2]=acc[s][3]=0.f; wsm[s]=0.f; }

  const size_t bbase = (size_t)b*NSEQ;
  const int nr0 = chunk*64 + w*2;
  uint4 k4; uint2 va, vb;
  {
    const size_t rowm = (bbase + nr0 + hi)*512;
    const size_t rowo = (bbase + nr0 + (1 - hi))*512;
    k4 = *(const uint4*)(kv + rowm + lo*8);
    va = *(const uint2*)(kv + rowm + 256 + (size_t)lane*4);
    vb = *(const uint2*)(kv + rowo + 256 + (size_t)lane*4);
  }
  for (int it = 0; it < 8; ++it){
    const int nr = nr0 + it*8;
    uint4 k4n; uint2 van, vbn;
    if (it < 7){
      const size_t rowmn = (bbase + nr + 8 + hi)*512;
      const size_t rowon = (bbase + nr + 8 + (1 - hi))*512;
      k4n = *(const uint4*)(kv + rowmn + lo*8);
      van = *(const uint2*)(kv + rowmn + 256 + (size_t)lane*4);
      vbn = *(const uint2*)(kv + rowon + 256 + (size_t)lane*4);
    }
    float kf[8];
    kf[0]=bflo(k4.x); kf[1]=bfhi(k4.x); kf[2]=bflo(k4.y); kf[3]=bfhi(k4.y);
    kf[4]=bflo(k4.z); kf[5]=bfhi(k4.z); kf[6]=bflo(k4.w); kf[7]=bfhi(k4.w);
    float z[7];
#pragma unroll
    for (int s = 0; s < 7; ++s){
      float d0 = fmaf(qr[s][0],kf[0], fmaf(qr[s][1],kf[1], fmaf(qr[s][2],kf[2], qr[s][3]*kf[3])));
      float d1 = fmaf(qr[s][4],kf[4], fmaf(qr[s][5],kf[5], fmaf(qr[s][6],kf[6], qr[s][7]*kf[7])));
      z[s] = d0 + d1;
    }
#pragma unroll
    for (int m = 1; m < 32; m <<= 1){
#pragma unroll
      for (int s = 0; s < 7; ++s) z[s] += __shfl_xor(z[s], m);
    }
    float zo[7];
#pragma unroll
    for (int s = 0; s < 7; ++s) zo[s] = __shfl_xor(z[s], 32);
    float pm[7], po[7];
    softmax7(z, pm);
    softmax7(zo, po);
    float sel = pm[0];
    sel = (lo==1)?pm[1]:sel; sel = (lo==2)?pm[2]:sel; sel = (lo==3)?pm[3]:sel;
    sel = (lo==4)?pm[4]:sel; sel = (lo==5)?pm[5]:sel; sel = (lo==6)?pm[6]:sel;
    if (lo < 7) attn_out[((size_t)bbase + nr + hi)*7 + lo] = sel;
    float vm0=bflo(va.x), vm1=bfhi(va.x), vm2=bflo(va.y), vm3=bfhi(va.y);
    float vo0=bflo(vb.x), vo1=bfhi(vb.x), vo2=bflo(vb.y), vo3=bfhi(vb.y);
#pragma unroll
    for (int s = 0; s < 7; ++s){
      acc[s][0] = fmaf(pm[s], vm0, fmaf(po[s], vo0, acc[s][0]));
      acc[s][1] = fmaf(pm[s], vm1, fmaf(po[s], vo1, acc[s][1]));
      acc[s][2] = fmaf(pm[s], vm2, fmaf(po[s], vo2, acc[s][2]));
      acc[s][3] = fmaf(pm[s], vm3, fmaf(po[s], vo3, acc[s][3]));
      wsm[s] += pm[s] + po[s];
    }
    if (it < 7){ k4 = k4n; va = van; vb = vbn; }
  }
#pragma unroll
  for (int s = 0; s < 7; ++s)
    *(f32x4*)&accbuf[w][s][lane*4] = (f32x4){acc[s][0], acc[s][1], acc[s][2], acc[s][3]};
  if (lane == 0){
#pragma unroll
    for (int s = 0; s < 7; ++s) wsbuf[w][s] = wsm[s];
  }
  __syncthreads();
#pragma unroll
  for (int s = 0; s < 7; ++s){
    float sum = accbuf[0][s][tid] + accbuf[1][s][tid] + accbuf[2][s][tid] + accbuf[3][s][tid];
    pacc[((size_t)chunk*NBAT + b)*(NSLOT*256) + s*256 + tid] = sum;
  }
  if (tid < 7)
    pw[((size_t)chunk*NBAT + b)*NSLOT + tid] =
        wsbuf[0][tid] + wsbuf[1][tid] + wsbuf[2][tid] + wsbuf[3][tid];
}

// ---------------- slotA: reduce pacc -> A2 = [bf16(updates) | bf16(slots_prev)] ----------------
__global__ __launch_bounds__(256) void k_slotA(
    const float* __restrict__ pacc, const float* __restrict__ pw,
    const float* __restrict__ slots, u16* __restrict__ A2, float* __restrict__ wsum){
  __shared__ float pwb[NCHUNK];
  const int r = blockIdx.x, t = threadIdx.x;
  if (r >= 224){
    A2[(size_t)r*512 + t] = 0;
    A2[(size_t)r*512 + 256 + t] = 0;
    return;
  }
  if (t < NCHUNK) pwb[t] = pw[(size_t)t*224 + r];
  float u = 0.f;
#pragma unroll 8
  for (int c = 0; c < NCHUNK; ++c) u += pacc[(size_t)c*57344 + (size_t)r*256 + t];
  __syncthreads();
  float wst = 0.f;
#pragma unroll
  for (int c = 0; c < NCHUNK; ++c) wst += pwb[c];
  if (t == 0) wsum[r] = wst;
  A2[(size_t)r*512 + t] = (u16)bf16rne(u / wst);
  A2[(size_t)r*512 + 256 + t] = (u16)bf16rne(slots[(size_t)r*256 + t]);
}

// ---------------- slotB: GRU elementwise + LN -> lnm bf16, snew f32 ----------------
__global__ __launch_bounds__(256) void k_slotB(
    const float* __restrict__ gates, const float* __restrict__ slots,
    const float* __restrict__ gm, const float* __restrict__ bm,
    float* __restrict__ snew, u16* __restrict__ lnm){
  __shared__ float red[8];
  const int r = blockIdx.x, t = threadIdx.x;
  if (r >= 224){ lnm[(size_t)r*256 + t] = 0; return; }
  const float g0  = gates[(size_t)r*1024 + t];
  const float g1  = gates[(size_t)r*1024 + 256 + t];
  const float gin = gates[(size_t)r*1024 + 512 + t];
  const float ghn = gates[(size_t)r*1024 + 768 + t];
  const float spv = slots[(size_t)r*256 + t];
  const float rr = 1.f/(1.f + __expf(-g0));
  const float zz = 1.f/(1.f + __expf(-g1));
  float xx = gin + rr*ghn;
  xx = fminf(fmaxf(xx, -15.f), 15.f);
  const float e2 = __expf(2.f*xx);
  const float nn = (e2 - 1.f)/(e2 + 1.f);
  const float sp = (1.f - zz)*nn + zz*spv;
  snew[(size_t)r*256 + t] = sp;
  float s = sp, s2 = sp*sp;
#pragma unroll
  for (int m = 1; m < 64; m <<= 1){ s += __shfl_xor(s, m); s2 += __shfl_xor(s2, m); }
  if ((t & 63) == 0){ red[t >> 6] = s; red[4 + (t >> 6)] = s2; }
  __syncthreads();
  const float ssum = red[0]+red[1]+red[2]+red[3];
  const float qsum = red[4]+red[5]+red[6]+red[7];
  const float mean = ssum*(1.f/256.f);
  const float var  = qsum*(1.f/256.f) - mean*mean;
  const float rstd = rsqrtf(var + 1e-5f);
  lnm[(size_t)r*256 + t] = (u16)bf16rne((sp - mean)*rstd*gm[t] + bm[t]);
}

// ---------------- lnq: LN(slots) -> lnq bf16 ----------------
__global__ __launch_bounds__(256) void k_lnq(
    const float* __restrict__ slots, const float* __restrict__ g, const float* __restrict__ b,
    u16* __restrict__ lnq){
  __shared__ float red[8];
  const int r = blockIdx.x, t = threadIdx.x;
  if (r >= 224){ lnq[(size_t)r*256 + t] = 0; return; }
  const float x = slots[(size_t)r*256 + t];
  float s = x, s2 = x*x;
#pragma unroll
  for (int m = 1; m < 64; m <<= 1){ s += __shfl_xor(s, m); s2 += __shfl_xor(s2, m); }
  if ((t & 63) == 0){ red[t >> 6] = s; red[4 + (t >> 6)] = s2; }
  __syncthreads();
  const float ssum = red[0]+red[1]+red[2]+red[3];
  const float qsum = red[4]+red[5]+red[6]+red[7];
  const float mean = ssum*(1.f/256.f);
  const float var  = qsum*(1.f/256.f) - mean*mean;
  const float rstd = rsqrtf(var + 1e-5f);
  lnq[(size_t)r*256 + t] = (u16)bf16rne((x - mean)*rstd*g[t] + b[t]);
}

// ---------------- K6: attn /= sum over n ----------------
__global__ __launch_bounds__(256) void k_norm(
    float* __restrict__ attn, const float* __restrict__ wsum_tot){
  size_t i = (size_t)blockIdx.x*256 + threadIdx.x;
  int s = (int)(i % 7);
  int b = (int)(i / (NSEQ*7));
  attn[i] = attn[i] / wsum_tot[b*7 + s];
}

// ---------------- launch ----------------
extern "C" void kernel_launch(void* const* d_in, const int* in_sizes, int n_in,
                              void* d_out, int out_size, void* d_ws, size_t ws_size,
                              hipStream_t stream){
  (void)in_sizes; (void)n_in; (void)out_size; (void)ws_size;
  const float* inputs  = (const float*)d_in[0];
  const float* noise   = (const float*)d_in[1];
  const float* ln_in_g = (const float*)d_in[2];
  const float* ln_in_b = (const float*)d_in[3];
  const float* ln_sl_g = (const float*)d_in[4];
  const float* ln_sl_b = (const float*)d_in[5];
  const float* ln_ml_g = (const float*)d_in[6];
  const float* ln_ml_b = (const float*)d_in[7];
  const float* mu      = (const float*)d_in[8];
  const float* sig     = (const float*)d_in[9];
  const float* wq      = (const float*)d_in[10];
  const float* bq      = (const float*)d_in[11];
  const float* wk      = (const float*)d_in[12];
  const float* bk      = (const float*)d_in[13];
  const float* wv      = (const float*)d_in[14];
  const float* bv      = (const float*)d_in[15];
  const float* w_ih    = (const float*)d_in[16];
  const float* b_ih    = (const float*)d_in[17];
  const float* w_hh    = (const float*)d_in[18];
  const float* b_hh    = (const float*)d_in[19];
  const float* w1      = (const float*)d_in[20];
  const float* b1      = (const float*)d_in[21];
  const float* w2      = (const float*)d_in[22];
  const float* b2      = (const float*)d_in[23];

  char* ws = (char*)d_ws;
  u16*   x_bf   = (u16*)(ws);                         // 67108864
  u16*   kv     = (u16*)(ws + 67108864);              // 134217728 -> ends 201326592
  char*  paccch = ws + 201326592;                     // 14680064 (pacc + aliased transients)
  float* pacc   = (float*)paccch;
  u16*   Wkv    = (u16*)(ws + 216006656);             // 262144
  float* qeff   = (float*)(ws + 216268800);           // 262144
  float* slots  = (float*)(ws + 216530944);           // 229376
  float* pw     = (float*)(ws + 216760320);           // 57344
  float* biaskv = (float*)(ws + 216817664);           // 2048
  float* wsum   = (float*)(ws + 216819712);           // 1024
  u16*   A2     = (u16*)(ws + 216820736);             // 262144
  u16*   Wg     = (u16*)(ws + 217082880);             // 1048576
  u16*   w1b    = (u16*)(ws + 218131456);             // 262144
  u16*   w2b    = (u16*)(ws + 218393600);             // 262144
  u16*   wqb    = (u16*)(ws + 218655744);             // 131072
  float* bg     = (float*)(ws + 218786816);           // 4096

  // transients aliased into pacc region (pacc dead between k_slotA and next k_attn;
  // lnq written by mlp2/lnq stage is consumed by qgemm BEFORE k_attn overwrites pacc)
  float* gates  = (float*)(paccch);                   // 1048576
  u16*   hb     = (u16*)(paccch + 1048576);           // 262144
  u16*   lnm    = (u16*)(paccch + 1310720);           // 131072
  u16*   lnq    = (u16*)(paccch + 1441792);           // 131072
  float* snew   = (float*)(paccch + 1572864);         // 229376

  float* out_slots = (float*)d_out;
  float* attn = (float*)d_out + 57344;

  k_prep<<<2786, 256, 0, stream>>>(wk, wv, bk, bv, mu, sig, noise,
                                   w_ih, b_ih, w_hh, b_hh, w1, w2, wq,
                                   Wkv, biaskv, slots, Wg, w1b, w2b, wqb, bg);
  k_ln_in<<<32768, 256, 0, stream>>>(inputs, ln_in_g, ln_in_b, x_bf);
  k_gemm_kv<<<4096, 256, 0, stream>>>(x_bf, Wkv, biaskv, kv);
  for (int i = 0; i < 3; ++i){
    const int last = (i == 2) ? 1 : 0;
    k_lnq<<<256, 256, 0, stream>>>(slots, ln_sl_g, ln_sl_b, lnq);
    k_gemm_s<3><<<dim3(2, 2), 256, 0, stream>>>(lnq, wqb, bq, 4, qeff, nullptr, nullptr, nullptr, 0);
    k_attn<<<dim3(NCHUNK, 32), 256, 0, stream>>>(kv, qeff, attn, pacc, pw);
    k_slotA<<<256, 256, 0, stream>>>(pacc, pw, slots, A2, wsum);
    k_gemm_s<0><<<dim3(8, 2), 256, 0, stream>>>(A2, Wg, bg, 8, gates, nullptr, nullptr, nullptr, 0);
    k_slotB<<<256, 256, 0, stream>>>(gates, slots, ln_ml_g, ln_ml_b, snew, lnm);
    k_gemm_s<1><<<dim3(4, 2), 256, 0, stream>>>(lnm, w1b, b1, 4, nullptr, hb, nullptr, nullptr, 0);
    k_gemm_s<2><<<dim3(2, 2), 256, 0, stream>>>(hb, w2b, b2, 8, slots, nullptr, snew, out_slots, last);
  }
  k_norm<<<3584, 256, 0, stream>>>(attn, wsum);
}

// Round 5
// 373.331 us; speedup vs baseline: 1.8030x; 1.1175x over previous
//
#include <hip/hip_runtime.h>
#include <stdint.h>

typedef unsigned short u16;
typedef unsigned int u32;
typedef float f32x4 __attribute__((ext_vector_type(4)));
typedef short short8 __attribute__((ext_vector_type(8)));

#define NBAT 32
#define NSEQ 4096
#define ND 256
#define NSLOT 7
#define NCHUNK 64

// ---------------- helpers ----------------
__device__ __forceinline__ u32 bf16rne(float f){
  u32 u = __float_as_uint(f);
  u = u + 0x7FFFu + ((u >> 16) & 1u);
  return u >> 16;
}
__device__ __forceinline__ u32 packbf(float a, float b){
  return (bf16rne(a) & 0xFFFFu) | (bf16rne(b) << 16);
}
__device__ __forceinline__ float bflo(u32 u){ return __uint_as_float(u << 16); }
__device__ __forceinline__ float bfhi(u32 u){ return __uint_as_float(u & 0xFFFF0000u); }

__device__ __forceinline__ void gld16(void* lds, const void* g){
  __builtin_amdgcn_global_load_lds(
      (const __attribute__((address_space(1))) u32*)g,
      (__attribute__((address_space(3))) u32*)lds, 16, 0, 0);
}

// ---------------- prep: bf16 weight copies, bias concat, slots init ----------------
__global__ __launch_bounds__(256) void k_prep(
    const float* __restrict__ wk, const float* __restrict__ wv,
    const float* __restrict__ bk, const float* __restrict__ bv,
    const float* __restrict__ mu, const float* __restrict__ sig,
    const float* __restrict__ noise,
    const float* __restrict__ w_ih, const float* __restrict__ b_ih,
    const float* __restrict__ w_hh, const float* __restrict__ b_hh,
    const float* __restrict__ w1, const float* __restrict__ w2,
    const float* __restrict__ wq,
    u16* __restrict__ Wkv, float* __restrict__ biaskv, float* __restrict__ slots,
    u16* __restrict__ Wg, u16* __restrict__ w1b, u16* __restrict__ w2b,
    u16* __restrict__ wqb, float* __restrict__ bg){
  const int bid = blockIdx.x, t = threadIdx.x;
  if (bid < 512){
    const float* src = (bid < 256) ? (wk + (size_t)bid*256) : (wv + (size_t)(bid-256)*256);
    Wkv[(size_t)bid*256 + t] = (u16)bf16rne(src[t]);
  } else if (bid == 512){
    biaskv[t] = bk[t];
    biaskv[256 + t] = bv[t];
  } else if (bid < 737){
    int r = bid - 513; // 0..223
    float sp = logf(1.f + expf(sig[t]));   // softplus
    slots[(size_t)r*256 + t] = mu[t] + sp * noise[(size_t)r*256 + t];
  } else if (bid < 1761){
    // Wg[1024][512]: rows 0-511 = [wih|whh]; 512-767 = [wih_n|0]; 768-1023 = [0|whh_n]
    int j = bid - 737;
    u16 a, b;
    if (j < 512){ a = (u16)bf16rne(w_ih[(size_t)j*256 + t]); b = (u16)bf16rne(w_hh[(size_t)j*256 + t]); }
    else if (j < 768){ a = (u16)bf16rne(w_ih[(size_t)j*256 + t]); b = 0; }
    else { a = 0; b = (u16)bf16rne(w_hh[(size_t)(j-256)*256 + t]); }
    Wg[(size_t)j*512 + t] = a;
    Wg[(size_t)j*512 + 256 + t] = b;
  } else if (bid < 2273){
    int j = bid - 1761; // 0..511
    w1b[(size_t)j*256 + t] = (u16)bf16rne(w1[(size_t)j*256 + t]);
  } else if (bid < 2529){
    int j = bid - 2273; // 0..255
    w2b[(size_t)j*512 + t]       = (u16)bf16rne(w2[(size_t)j*512 + t]);
    w2b[(size_t)j*512 + 256 + t] = (u16)bf16rne(w2[(size_t)j*512 + 256 + t]);
  } else if (bid < 2785){
    int j = bid - 2529; // 0..255
    wqb[(size_t)j*256 + t] = (u16)bf16rne(wq[(size_t)j*256 + t]);
  } else {
#pragma unroll
    for (int ii = 0; ii < 4; ++ii){
      int j = ii*256 + t;
      float v;
      if (j < 512) v = b_ih[j] + b_hh[j];
      else if (j < 768) v = b_ih[j];
      else v = b_hh[j - 256];
      bg[j] = v;
    }
  }
}

// ---------------- K1: LayerNorm(inputs) -> x bf16, one wave per row ----------------
__global__ __launch_bounds__(256) void k_ln_in(
    const float* __restrict__ x, const float* __restrict__ g, const float* __restrict__ b,
    u16* __restrict__ xo){
  const int row = blockIdx.x*4 + (threadIdx.x >> 6);
  const int lane = threadIdx.x & 63;
  const f32x4 v = *(const f32x4*)(x + (size_t)row*ND + lane*4);
  float s  = v[0]+v[1]+v[2]+v[3];
  float s2 = v[0]*v[0]+v[1]*v[1]+v[2]*v[2]+v[3]*v[3];
#pragma unroll
  for (int m = 1; m < 64; m <<= 1){ s += __shfl_xor(s, m); s2 += __shfl_xor(s2, m); }
  const float mean = s * (1.f/256.f);
  const float var  = s2 * (1.f/256.f) - mean*mean;
  const float rstd = rsqrtf(var + 1e-5f);
  const f32x4 gg = *(const f32x4*)(g + lane*4);
  const f32x4 bb = *(const f32x4*)(b + lane*4);
  float y0 = (v[0]-mean)*rstd*gg[0] + bb[0];
  float y1 = (v[1]-mean)*rstd*gg[1] + bb[1];
  float y2 = (v[2]-mean)*rstd*gg[2] + bb[2];
  float y3 = (v[3]-mean)*rstd*gg[3] + bb[3];
  uint2 o; o.x = packbf(y0, y1); o.y = packbf(y2, y3);
  *(uint2*)(xo + (size_t)row*ND + lane*4) = o;
}

// ---------------- K2: kv = x @ Wkv^T + bias (MFMA bf16, 128x128, dbuf 2-phase, XCD swz) ----
__global__ __launch_bounds__(256) void k_gemm_kv(
    const u16* __restrict__ X, const u16* __restrict__ W,
    const float* __restrict__ biaskv, u16* __restrict__ kv){
  __shared__ __align__(16) u16 At[2][128*64];
  __shared__ __align__(16) u16 Bt[2][128*64];
  const int bid = blockIdx.x;                 // 0..4095
  const int swz = ((bid & 7) << 9) + (bid >> 3);
  const int mb = swz >> 2, nb = swz & 3;
  const int tid = threadIdx.x, w = tid >> 6, lane = tid & 63;
  const int wm = w >> 1, wn = w & 1;
  f32x4 acc[4][4];
#pragma unroll
  for (int a = 0; a < 4; ++a)
#pragma unroll
    for (int c = 0; c < 4; ++c) acc[a][c] = (f32x4){0.f,0.f,0.f,0.f};

  const int cl = lane & 7;
#define STAGE_KV(buf, kt)                                                        \
  {                                                                              \
    _Pragma("unroll")                                                            \
    for (int i = 0; i < 4; ++i){                                                 \
      int R = w*32 + i*8 + (lane >> 3);                                          \
      int c = cl ^ (R & 7);                                                      \
      gld16(&At[buf][(w*32 + i*8)*64], X + ((size_t)(mb*128 + R))*256 + (kt)*64 + c*8); \
      gld16(&Bt[buf][(w*32 + i*8)*64], W + ((size_t)(nb*128 + R))*256 + (kt)*64 + c*8); \
    }                                                                            \
  }
  STAGE_KV(0, 0);
  __syncthreads();
  for (int kt = 0; kt < 4; ++kt){
    const int cur = kt & 1;
    if (kt < 3) STAGE_KV(cur ^ 1, kt + 1);
#pragma unroll
    for (int kk = 0; kk < 2; ++kk){
      short8 xf[4], wf[4];
#pragma unroll
      for (int xi = 0; xi < 4; ++xi){
        int r = wm*64 + xi*16 + (lane & 15);
        int ch = (kk*4 + (lane >> 4)) ^ (r & 7);
        xf[xi] = *(const short8*)&At[cur][r*64 + ch*8];
      }
#pragma unroll
      for (int wi = 0; wi < 4; ++wi){
        int r = wn*64 + wi*16 + (lane & 15);
        int ch = (kk*4 + (lane >> 4)) ^ (r & 7);
        wf[wi] = *(const short8*)&Bt[cur][r*64 + ch*8];
      }
#pragma unroll
      for (int xi = 0; xi < 4; ++xi)
#pragma unroll
        for (int wi = 0; wi < 4; ++wi)
          acc[xi][wi] = __builtin_amdgcn_mfma_f32_16x16x32_bf16(wf[wi], xf[xi], acc[xi][wi], 0, 0, 0);
    }
    __syncthreads();
  }
#undef STAGE_KV
  f32x4 bias[4];
#pragma unroll
  for (int wi = 0; wi < 4; ++wi)
    bias[wi] = *(const f32x4*)(biaskv + nb*128 + wn*64 + wi*16 + (lane >> 4)*4);
#pragma unroll
  for (int xi = 0; xi < 4; ++xi){
    size_t m = (size_t)mb*128 + wm*64 + xi*16 + (lane & 15);
    u16* dst = kv + m*512 + nb*128 + wn*64 + (lane >> 4)*4;
#pragma unroll
    for (int wi = 0; wi < 4; ++wi){
      f32x4 c = acc[xi][wi];
      uint2 o;
      o.x = packbf(c[0] + bias[wi][0], c[1] + bias[wi][1]);
      o.y = packbf(c[2] + bias[wi][2], c[3] + bias[wi][3]);
      *(uint2*)(dst + wi*16) = o;
    }
  }
}

// ---------------- small-GEMM (MFMA, 128x128, dbuf 2-phase): out = A @ W^T + bias ----
// MODE 0: gates, f32 out ld=1024
// MODE 1: mlp1, relu -> bf16 out ld=512
// MODE 2: mlp2, + snew + bias -> slots f32 ld=256 (rows<224), optional out_slots copy
// MODE 3: qproj, (acc+bias)*log2(e)/16 -> BF16 out ld=256
template<int MODE>
__global__ __launch_bounds__(256) void k_gemm_s(
    const u16* __restrict__ A, const u16* __restrict__ W,
    const float* __restrict__ bias, int nkt,
    float* __restrict__ outf, u16* __restrict__ outb,
    const float* __restrict__ snew, float* __restrict__ out2, int last){
  __shared__ __align__(16) u16 At[2][128*64];
  __shared__ __align__(16) u16 Bt[2][128*64];
  const int nb = blockIdx.x, mb = blockIdx.y;
  const int tid = threadIdx.x, w = tid >> 6, lane = tid & 63;
  const int wm = w >> 1, wn = w & 1;
  const size_t K = (size_t)nkt * 64;
  f32x4 acc[4][4];
#pragma unroll
  for (int a = 0; a < 4; ++a)
#pragma unroll
    for (int c = 0; c < 4; ++c) acc[a][c] = (f32x4){0.f,0.f,0.f,0.f};

  const int cl = lane & 7;
#define STAGE_S(buf, kt)                                                         \
  {                                                                              \
    _Pragma("unroll")                                                            \
    for (int i = 0; i < 4; ++i){                                                 \
      int R = w*32 + i*8 + (lane >> 3);                                          \
      int c = cl ^ (R & 7);                                                      \
      gld16(&At[buf][(w*32 + i*8)*64], A + ((size_t)(mb*128 + R))*K + (kt)*64 + c*8); \
      gld16(&Bt[buf][(w*32 + i*8)*64], W + ((size_t)(nb*128 + R))*K + (kt)*64 + c*8); \
    }                                                                            \
  }
  STAGE_S(0, 0);
  __syncthreads();
  for (int kt = 0; kt < nkt; ++kt){
    const int cur = kt & 1;
    if (kt < nkt - 1) STAGE_S(cur ^ 1, kt + 1);
#pragma unroll
    for (int kk = 0; kk < 2; ++kk){
      short8 xf[4], wf[4];
#pragma unroll
      for (int xi = 0; xi < 4; ++xi){
        int r = wm*64 + xi*16 + (lane & 15);
        int ch = (kk*4 + (lane >> 4)) ^ (r & 7);
        xf[xi] = *(const short8*)&At[cur][r*64 + ch*8];
      }
#pragma unroll
      for (int wi = 0; wi < 4; ++wi){
        int r = wn*64 + wi*16 + (lane & 15);
        int ch = (kk*4 + (lane >> 4)) ^ (r & 7);
        wf[wi] = *(const short8*)&Bt[cur][r*64 + ch*8];
      }
#pragma unroll
      for (int xi = 0; xi < 4; ++xi)
#pragma unroll
        for (int wi = 0; wi < 4; ++wi)
          acc[xi][wi] = __builtin_amdgcn_mfma_f32_16x16x32_bf16(wf[wi], xf[xi], acc[xi][wi], 0, 0, 0);
    }
    __syncthreads();
  }
#undef STAGE_S
  const int LDO = (MODE == 0) ? 1024 : ((MODE == 1) ? 512 : 256);
  f32x4 b4[4];
#pragma unroll
  for (int wi = 0; wi < 4; ++wi)
    b4[wi] = *(const f32x4*)(bias + nb*128 + wn*64 + wi*16 + (lane >> 4)*4);
#pragma unroll
  for (int xi = 0; xi < 4; ++xi){
    const int m = mb*128 + wm*64 + xi*16 + (lane & 15);
    const int colb = nb*128 + wn*64 + (lane >> 4)*4;
#pragma unroll
    for (int wi = 0; wi < 4; ++wi){
      const int col = colb + wi*16;
      f32x4 c = acc[xi][wi] + b4[wi];
      if (MODE == 0){
        *(f32x4*)(outf + (size_t)m*LDO + col) = c;
      } else if (MODE == 1){
        uint2 o;
        o.x = packbf(fmaxf(c[0],0.f), fmaxf(c[1],0.f));
        o.y = packbf(fmaxf(c[2],0.f), fmaxf(c[3],0.f));
        *(uint2*)(outb + (size_t)m*LDO + col) = o;
      } else if (MODE == 2){
        if (m < 224){
          const f32x4 s4 = *(const f32x4*)(snew + (size_t)m*256 + col);
          f32x4 o = c + s4;
          *(f32x4*)(outf + (size_t)m*LDO + col) = o;
          if (last) *(f32x4*)(out2 + (size_t)m*LDO + col) = o;
        }
      } else { // MODE 3: bf16 q, pre-scaled
        uint2 o;
        o.x = packbf(c[0]*0.09016844f, c[1]*0.09016844f);
        o.y = packbf(c[2]*0.09016844f, c[3]*0.09016844f);
        *(uint2*)(outb + (size_t)m*LDO + col) = o;
      }
    }
  }
}

// ---------------- K4: MFMA QK^T -> softmax(S) -> VALU PV; partials out ----------------
// grid (64 chunks, 32 b); block 256 = 4 waves; wave w owns rows chunk*64 + w*16 .. +15.
// QK^T: mfma(Q, K): slot = (lane>>4)*4+reg, n = lane&15 (layout verified in k_gemm).
// K frags read direct from global (4-lane groups consume full 64B lines -> coalesced).
__global__ __launch_bounds__(256) void k_attn(
    const u16* __restrict__ kv, const u16* __restrict__ qb,
    float* __restrict__ attn_out, float* __restrict__ pacc, float* __restrict__ pw){
  __shared__ __align__(16) float accbuf[4][7][256];   // 28 KB
  __shared__ __align__(16) float p_lds[4][16][8];     // 2 KB
  __shared__ float wsum_lds[4][8];
  const int chunk = blockIdx.x, b = blockIdx.y;
  const int tid = threadIdx.x, w = tid >> 6, lane = tid & 63;
  const int l15 = lane & 15, g = lane >> 4, hi = lane >> 5;
  const size_t bbase = (size_t)b*NSEQ;
  const int nr0 = chunk*64 + w*16;   // wave's first row

  // ---- Q fragments (bf16, pre-scaled). rows >= 7 are other-batch garbage, masked below.
  short8 qf[8];
  {
    const u16* qrow = qb + ((size_t)b*7 + l15)*256;
#pragma unroll
    for (int ks = 0; ks < 8; ++ks)
      qf[ks] = *(const short8*)(qrow + (ks*4 + g)*8);
  }
  // ---- QK^T: 8 MFMA over K=256
  f32x4 z = {0.f,0.f,0.f,0.f};
#pragma unroll
  for (int ks = 0; ks < 8; ++ks){
    const short8 kf = *(const short8*)(kv + (bbase + nr0 + l15)*512 + (ks*4 + g)*8);
    z = __builtin_amdgcn_mfma_f32_16x16x32_bf16(qf[ks], kf, z, 0, 0, 0);
  }
  // ---- softmax over slots (7 real). lane group g holds slots g*4+j for col n=l15.
  float zz[4];
#pragma unroll
  for (int j = 0; j < 4; ++j){
    const int s = g*4 + j;
    zz[j] = (s < 7) ? z[j] : -3.0e38f;
  }
  float mx = fmaxf(fmaxf(zz[0], zz[1]), fmaxf(zz[2], zz[3]));
  mx = fmaxf(mx, __shfl_xor(mx, 16));
  float p[4], psum = 0.f;
#pragma unroll
  for (int j = 0; j < 4; ++j){ p[j] = exp2f(zz[j] - mx); psum += p[j]; }
  psum += __shfl_xor(psum, 16);
  const float rs = 1.f / psum;
#pragma unroll
  for (int j = 0; j < 4; ++j) p[j] = fmaf(p[j], rs, 1e-8f);
  float wloc[4] = {0.f,0.f,0.f,0.f};
  if (lane < 32){
    *(f32x4*)&p_lds[w][l15][g*4] = (f32x4){p[0], p[1], p[2], p[3]};
    const size_t arow = (bbase + nr0 + l15)*7;
#pragma unroll
    for (int j = 0; j < 4; ++j){
      const int s = g*4 + j;
      if (s < 7){ attn_out[arow + s] = p[j]; wloc[j] = p[j]; }
    }
  }
  __syncthreads();
  // ---- PV (VALU): wave covers its 16 rows, 2 per iter; lane owns d = lane*4..+3
  float acc[7][4];
#pragma unroll
  for (int s = 0; s < 7; ++s){ acc[s][0]=acc[s][1]=acc[s][2]=acc[s][3]=0.f; }
#pragma unroll
  for (int it = 0; it < 8; ++it){
    const int rm = it*2 + hi, ro = it*2 + (1 - hi);
    const uint2 va = *(const uint2*)(kv + (bbase + nr0 + rm)*512 + 256 + (size_t)lane*4);
    const uint2 vb = *(const uint2*)(kv + (bbase + nr0 + ro)*512 + 256 + (size_t)lane*4);
    const f32x4 pm0 = *(const f32x4*)&p_lds[w][rm][0];
    const f32x4 pm1 = *(const f32x4*)&p_lds[w][rm][4];
    const f32x4 po0 = *(const f32x4*)&p_lds[w][ro][0];
    const f32x4 po1 = *(const f32x4*)&p_lds[w][ro][4];
    const float pm[7] = {pm0[0],pm0[1],pm0[2],pm0[3],pm1[0],pm1[1],pm1[2]};
    const float po[7] = {po0[0],po0[1],po0[2],po0[3],po1[0],po1[1],po1[2]};
    const float vm0=bflo(va.x), vm1=bfhi(va.x), vm2=bflo(va.y), vm3=bfhi(va.y);
    const float vo0=bflo(vb.x), vo1=bfhi(vb.x), vo2=bflo(vb.y), vo3=bfhi(vb.y);
#pragma unroll
    for (int s = 0; s < 7; ++s){
      acc[s][0] = fmaf(pm[s], vm0, fmaf(po[s], vo0, acc[s][0]));
      acc[s][1] = fmaf(pm[s], vm1, fmaf(po[s], vo1, acc[s][1]));
      acc[s][2] = fmaf(pm[s], vm2, fmaf(po[s], vo2, acc[s][2]));
      acc[s][3] = fmaf(pm[s], vm3, fmaf(po[s], vo3, acc[s][3]));
    }
  }
  // ---- wsm: reduce wloc over n (lanes 0..15 within each half-wave group)
#pragma unroll
  for (int m = 1; m < 16; m <<= 1){
#pragma unroll
    for (int j = 0; j < 4; ++j) wloc[j] += __shfl_xor(wloc[j], m);
  }
  if (lane < 32 && l15 == 0){
#pragma unroll
    for (int j = 0; j < 4; ++j) wsum_lds[w][g*4 + j] = wloc[j];
  }
  __syncthreads();
  // ---- cross-wave reduce of PV partials
#pragma unroll
  for (int s = 0; s < 7; ++s)
    *(f32x4*)&accbuf[w][s][lane*4] = (f32x4){acc[s][0], acc[s][1], acc[s][2], acc[s][3]};
  __syncthreads();
#pragma unroll
  for (int s = 0; s < 7; ++s){
    float sum = accbuf[0][s][tid] + accbuf[1][s][tid] + accbuf[2][s][tid] + accbuf[3][s][tid];
    pacc[((size_t)chunk*NBAT + b)*(NSLOT*256) + s*256 + tid] = sum;
  }
  if (tid < 7)
    pw[((size_t)chunk*NBAT + b)*NSLOT + tid] =
        wsum_lds[0][tid] + wsum_lds[1][tid] + wsum_lds[2][tid] + wsum_lds[3][tid];
}

// ---------------- slotA: reduce pacc -> A2 = [bf16(updates) | bf16(slots_prev)] ----------------
__global__ __launch_bounds__(256) void k_slotA(
    const float* __restrict__ pacc, const float* __restrict__ pw,
    const float* __restrict__ slots, u16* __restrict__ A2, float* __restrict__ wsum){
  __shared__ float pwb[NCHUNK];
  const int r = blockIdx.x, t = threadIdx.x;
  if (r >= 224){
    A2[(size_t)r*512 + t] = 0;
    A2[(size_t)r*512 + 256 + t] = 0;
    return;
  }
  if (t < NCHUNK) pwb[t] = pw[(size_t)t*224 + r];
  float u = 0.f;
#pragma unroll 8
  for (int c = 0; c < NCHUNK; ++c) u += pacc[(size_t)c*57344 + (size_t)r*256 + t];
  __syncthreads();
  float wst = 0.f;
#pragma unroll
  for (int c = 0; c < NCHUNK; ++c) wst += pwb[c];
  if (t == 0) wsum[r] = wst;
  A2[(size_t)r*512 + t] = (u16)bf16rne(u / wst);
  A2[(size_t)r*512 + 256 + t] = (u16)bf16rne(slots[(size_t)r*256 + t]);
}

// ---------------- slotB: GRU elementwise + LN -> lnm bf16, snew f32 ----------------
__global__ __launch_bounds__(256) void k_slotB(
    const float* __restrict__ gates, const float* __restrict__ slots,
    const float* __restrict__ gm, const float* __restrict__ bm,
    float* __restrict__ snew, u16* __restrict__ lnm){
  __shared__ float red[8];
  const int r = blockIdx.x, t = threadIdx.x;
  if (r >= 224){ lnm[(size_t)r*256 + t] = 0; return; }
  const float g0  = gates[(size_t)r*1024 + t];
  const float g1  = gates[(size_t)r*1024 + 256 + t];
  const float gin = gates[(size_t)r*1024 + 512 + t];
  const float ghn = gates[(size_t)r*1024 + 768 + t];
  const float spv = slots[(size_t)r*256 + t];
  const float rr = 1.f/(1.f + __expf(-g0));
  const float zz = 1.f/(1.f + __expf(-g1));
  float xx = gin + rr*ghn;
  xx = fminf(fmaxf(xx, -15.f), 15.f);
  const float e2 = __expf(2.f*xx);
  const float nn = (e2 - 1.f)/(e2 + 1.f);
  const float sp = (1.f - zz)*nn + zz*spv;
  snew[(size_t)r*256 + t] = sp;
  float s = sp, s2 = sp*sp;
#pragma unroll
  for (int m = 1; m < 64; m <<= 1){ s += __shfl_xor(s, m); s2 += __shfl_xor(s2, m); }
  if ((t & 63) == 0){ red[t >> 6] = s; red[4 + (t >> 6)] = s2; }
  __syncthreads();
  const float ssum = red[0]+red[1]+red[2]+red[3];
  const float qsum = red[4]+red[5]+red[6]+red[7];
  const float mean = ssum*(1.f/256.f);
  const float var  = qsum*(1.f/256.f) - mean*mean;
  const float rstd = rsqrtf(var + 1e-5f);
  lnm[(size_t)r*256 + t] = (u16)bf16rne((sp - mean)*rstd*gm[t] + bm[t]);
}

// ---------------- lnq: LN(slots) -> lnq bf16 ----------------
__global__ __launch_bounds__(256) void k_lnq(
    const float* __restrict__ slots, const float* __restrict__ g, const float* __restrict__ b,
    u16* __restrict__ lnq){
  __shared__ float red[8];
  const int r = blockIdx.x, t = threadIdx.x;
  if (r >= 224){ lnq[(size_t)r*256 + t] = 0; return; }
  const float x = slots[(size_t)r*256 + t];
  float s = x, s2 = x*x;
#pragma unroll
  for (int m = 1; m < 64; m <<= 1){ s += __shfl_xor(s, m); s2 += __shfl_xor(s2, m); }
  if ((t & 63) == 0){ red[t >> 6] = s; red[4 + (t >> 6)] = s2; }
  __syncthreads();
  const float ssum = red[0]+red[1]+red[2]+red[3];
  const float qsum = red[4]+red[5]+red[6]+red[7];
  const float mean = ssum*(1.f/256.f);
  const float var  = qsum*(1.f/256.f) - mean*mean;
  const float rstd = rsqrtf(var + 1e-5f);
  lnq[(size_t)r*256 + t] = (u16)bf16rne((x - mean)*rstd*g[t] + b[t]);
}

// ---------------- K6: attn /= sum over n ----------------
__global__ __launch_bounds__(256) void k_norm(
    float* __restrict__ attn, const float* __restrict__ wsum_tot){
  size_t i = (size_t)blockIdx.x*256 + threadIdx.x;
  int s = (int)(i % 7);
  int b = (int)(i / (NSEQ*7));
  attn[i] = attn[i] / wsum_tot[b*7 + s];
}

// ---------------- launch ----------------
extern "C" void kernel_launch(void* const* d_in, const int* in_sizes, int n_in,
                              void* d_out, int out_size, void* d_ws, size_t ws_size,
                              hipStream_t stream){
  (void)in_sizes; (void)n_in; (void)out_size; (void)ws_size;
  const float* inputs  = (const float*)d_in[0];
  const float* noise   = (const float*)d_in[1];
  const float* ln_in_g = (const float*)d_in[2];
  const float* ln_in_b = (const float*)d_in[3];
  const float* ln_sl_g = (const float*)d_in[4];
  const float* ln_sl_b = (const float*)d_in[5];
  const float* ln_ml_g = (const float*)d_in[6];
  const float* ln_ml_b = (const float*)d_in[7];
  const float* mu      = (const float*)d_in[8];
  const float* sig     = (const float*)d_in[9];
  const float* wq      = (const float*)d_in[10];
  const float* bq      = (const float*)d_in[11];
  const float* wk      = (const float*)d_in[12];
  const float* bk      = (const float*)d_in[13];
  const float* wv      = (const float*)d_in[14];
  const float* bv      = (const float*)d_in[15];
  const float* w_ih    = (const float*)d_in[16];
  const float* b_ih    = (const float*)d_in[17];
  const float* w_hh    = (const float*)d_in[18];
  const float* b_hh    = (const float*)d_in[19];
  const float* w1      = (const float*)d_in[20];
  const float* b1      = (const float*)d_in[21];
  const float* w2      = (const float*)d_in[22];
  const float* b2      = (const float*)d_in[23];

  char* ws = (char*)d_ws;
  u16*   x_bf   = (u16*)(ws);                         // 67108864
  u16*   kv     = (u16*)(ws + 67108864);              // 134217728 -> ends 201326592
  char*  paccch = ws + 201326592;                     // 14680064 (pacc; transients alias below)
  float* pacc   = (float*)paccch;
  u16*   Wkv    = (u16*)(ws + 216006656);             // 262144
  u16*   qeffb  = (u16*)(ws + 216268800);             // 131072 (256 rows bf16)
  float* slots  = (float*)(ws + 216530944);           // 229376
  float* pw     = (float*)(ws + 216760320);           // 57344
  float* biaskv = (float*)(ws + 216817664);           // 2048
  float* wsum   = (float*)(ws + 216819712);           // 1024
  u16*   A2     = (u16*)(ws + 216820736);             // 262144
  u16*   Wg     = (u16*)(ws + 217082880);             // 1048576
  u16*   w1b    = (u16*)(ws + 218131456);             // 262144
  u16*   w2b    = (u16*)(ws + 218393600);             // 262144
  u16*   wqb    = (u16*)(ws + 218655744);             // 131072
  float* bg     = (float*)(ws + 218786816);           // 4096

  // transients aliased into pacc region (dead between slotA and next attn)
  float* gates  = (float*)(paccch);                   // 1048576
  u16*   hb     = (u16*)(paccch + 1048576);           // 262144
  u16*   lnm    = (u16*)(paccch + 1310720);           // 131072
  u16*   lnq    = (u16*)(paccch + 1441792);           // 131072
  float* snew   = (float*)(paccch + 1572864);         // 229376

  float* out_slots = (float*)d_out;
  float* attn = (float*)d_out + 57344;

  k_prep<<<2786, 256, 0, stream>>>(wk, wv, bk, bv, mu, sig, noise,
                                   w_ih, b_ih, w_hh, b_hh, w1, w2, wq,
                                   Wkv, biaskv, slots, Wg, w1b, w2b, wqb, bg);
  k_ln_in<<<32768, 256, 0, stream>>>(inputs, ln_in_g, ln_in_b, x_bf);
  k_gemm_kv<<<4096, 256, 0, stream>>>(x_bf, Wkv, biaskv, kv);
  for (int i = 0; i < 3; ++i){
    const int last = (i == 2) ? 1 : 0;
    k_lnq<<<256, 256, 0, stream>>>(slots, ln_sl_g, ln_sl_b, lnq);
    k_gemm_s<3><<<dim3(2, 2), 256, 0, stream>>>(lnq, wqb, bq, 4, nullptr, qeffb, nullptr, nullptr, 0);
    k_attn<<<dim3(NCHUNK, 32), 256, 0, stream>>>(kv, qeffb, attn, pacc, pw);
    k_slotA<<<256, 256, 0, stream>>>(pacc, pw, slots, A2, wsum);
    k_gemm_s<0><<<dim3(8, 2), 256, 0, stream>>>(A2, Wg, bg, 8, gates, nullptr, nullptr, nullptr, 0);
    k_slotB<<<256, 256, 0, stream>>>(gates, slots, ln_ml_g, ln_ml_b, snew, lnm);
    k_gemm_s<1><<<dim3(4, 2), 256, 0, stream>>>(lnm, w1b, b1, 4, nullptr, hb, nullptr, nullptr, 0);
    k_gemm_s<2><<<dim3(2, 2), 256, 0, stream>>>(hb, w2b, b2, 8, slots, nullptr, snew, out_slots, last);
  }
  k_norm<<<3584, 256, 0, stream>>>(attn, wsum);
}